// Round 1
// baseline (1140.611 us; speedup 1.0000x reference)
//
#include <hip/hip_runtime.h>
#include <hip/hip_bf16.h>
#include <math.h>

// Problem constants (B=4, T=2048 -> N=8192 tokens)
#define N_TOK 8192
#define DIM   1024
#define E_R   32      // routed experts
#define H_E   128     // per-expert hidden
#define HS    512     // shared hidden = 4 chunks of 128
#define TOPK  4
#define NEXP  36      // 32 routed + 4 shared chunks

typedef __bf16 bf16;
typedef __bf16 bf16x8 __attribute__((ext_vector_type(8)));
typedef __bf16 bf16x4 __attribute__((ext_vector_type(4)));
typedef float  floatx4 __attribute__((ext_vector_type(4)));

// ---------------------------------------------------------------- convert
__global__ void cvt_f32_bf16(const float* __restrict__ src,
                             bf16* __restrict__ dst, int n) {
    int i = (blockIdx.x * blockDim.x + threadIdx.x) * 4;
    if (i < n) {
        float4 v = *(const float4*)(src + i);
        bf16x4 o = { (bf16)v.x, (bf16)v.y, (bf16)v.z, (bf16)v.w };
        *(bf16x4*)(dst + i) = o;
    }
}

// ---------------------------------------------------------------- router
// One wave per token. fp32 logits (must match reference selection).
__global__ __launch_bounds__(64)
void router_kernel(const float* __restrict__ x,
                   const float* __restrict__ rw,
                   const float* __restrict__ rb,
                   int* __restrict__ counts,
                   int* __restrict__ tlist,
                   float* __restrict__ slist) {
    int n = blockIdx.x;
    int lane = threadIdx.x;
    __shared__ float lds[E_R];

    float xr[16];
#pragma unroll
    for (int i = 0; i < 16; ++i) xr[i] = x[(size_t)n * DIM + lane + i * 64];

    for (int e = 0; e < E_R; ++e) {
        const float* w = rw + (size_t)e * DIM;
        float p = 0.f;
#pragma unroll
        for (int i = 0; i < 16; ++i) p += xr[i] * w[lane + i * 64];
#pragma unroll
        for (int off = 32; off; off >>= 1) p += __shfl_xor(p, off);
        if (lane == 0) lds[e] = p + rb[e];
    }
    __syncthreads();

    if (lane == 0) {
        float mx = -1e30f;
        for (int e = 0; e < E_R; ++e) mx = fmaxf(mx, lds[e]);
        float se = 0.f;
        for (int e = 0; e < E_R; ++e) { float v = expf(lds[e] - mx); lds[e] = v; se += v; }
        float inv = 1.f / se;
        // top-4 (strict > : lowest index wins ties, matches lax.top_k)
        unsigned usedMask = 0;
        int   idx[TOPK];
        float pv[TOPK];
        float psum = 0.f;
        for (int k = 0; k < TOPK; ++k) {
            float best = -1.f; int bi = 0;
            for (int e = 0; e < E_R; ++e) {
                if (!((usedMask >> e) & 1) && lds[e] > best) { best = lds[e]; bi = e; }
            }
            usedMask |= 1u << bi;
            idx[k] = bi; pv[k] = best * inv; psum += pv[k];
        }
        float norm = 1.f / fmaxf(psum, 1e-12f);
        for (int k = 0; k < TOPK; ++k) {
            int e = idx[k];
            int pos = atomicAdd(&counts[e], 1);
            tlist[(size_t)e * N_TOK + pos] = n;
            slist[(size_t)e * N_TOK + pos] = pv[k] * norm;
        }
    }
}

// ---------------------------------------------------------------- FFN
// blockIdx.y = "expert" (0..31 routed, 32..35 shared chunk)
// blockIdx.x = 64-token tile. 256 threads = 4 waves (16 M-rows each).
#define TM 64
#define BK 32
#define A_STRIDE 40    // bf16 elems; 80B rows, 16B aligned groups
#define H_STRIDE 136   // bf16 elems; 272B rows, 16B aligned groups

__global__ __launch_bounds__(256)
void ffn_kernel(const bf16* __restrict__ xb,
                const bf16* __restrict__ wg,   // [32][128][1024]
                const bf16* __restrict__ wu,
                const bf16* __restrict__ wd,   // [32][1024][128]
                const bf16* __restrict__ sg,   // [512][1024]
                const bf16* __restrict__ su,
                const bf16* __restrict__ sd,   // [1024][512]
                const int*  __restrict__ counts,
                const int*  __restrict__ tlist,
                const float* __restrict__ slist,
                float* __restrict__ out) {
    int e  = blockIdx.y;
    int t0 = blockIdx.x * TM;
    bool routed = (e < E_R);
    int Ne = routed ? counts[e] : N_TOK;
    if (t0 >= Ne) return;

    const bf16 *gptr, *uptr, *dptr;
    int dstride;
    if (routed) {
        gptr = wg + (size_t)e * H_E * DIM;
        uptr = wu + (size_t)e * H_E * DIM;
        dptr = wd + (size_t)e * DIM * H_E;
        dstride = H_E;
    } else {
        int c = e - E_R;
        gptr = sg + (size_t)c * H_E * DIM;   // rows c*128..c*128+127
        uptr = su + (size_t)c * H_E * DIM;
        dptr = sd + (size_t)c * H_E;         // column block, row stride HS
        dstride = HS;
    }

    __shared__ int   stok[TM];
    __shared__ float ssc[TM];
    __shared__ bf16  Abuf[TM][A_STRIDE];
    __shared__ bf16  hbuf[TM][H_STRIDE];

    int tid = threadIdx.x;
    if (tid < TM) {
        int r = t0 + tid;
        if (r < Ne) {
            stok[tid] = routed ? tlist[(size_t)e * N_TOK + r] : r;
            ssc[tid]  = routed ? slist[(size_t)e * N_TOK + r] : 1.0f;
        } else { stok[tid] = 0; ssc[tid] = 0.f; }
    }
    __syncthreads();

    int w    = tid >> 6;
    int lane = tid & 63;
    int m    = lane & 15;
    int quad = lane >> 4;

    // ---------- phase 1: gate/up GEMM, M=64, N=128, K=1024 ----------
    floatx4 accG[8] = {};
    floatx4 accU[8] = {};
    int arow = tid >> 2;            // 0..63
    int acol = (tid & 3) * 8;       // 0,8,16,24
    const bf16* asrc = xb + (size_t)stok[arow] * DIM + acol;

    for (int k0 = 0; k0 < DIM; k0 += BK) {
        *(bf16x8*)(&Abuf[arow][acol]) = *(const bf16x8*)(asrc + k0);
        __syncthreads();
        bf16x8 af = *(const bf16x8*)(&Abuf[w * 16 + m][quad * 8]);
        const bf16* gk = gptr + (size_t)m * DIM + k0 + quad * 8;
        const bf16* uk = uptr + (size_t)m * DIM + k0 + quad * 8;
#pragma unroll
        for (int nt = 0; nt < 8; ++nt) {
            bf16x8 bg = *(const bf16x8*)(gk + (size_t)nt * 16 * DIM);
            bf16x8 bu = *(const bf16x8*)(uk + (size_t)nt * 16 * DIM);
            accG[nt] = __builtin_amdgcn_mfma_f32_16x16x32_bf16(af, bg, accG[nt], 0, 0, 0);
            accU[nt] = __builtin_amdgcn_mfma_f32_16x16x32_bf16(af, bu, accU[nt], 0, 0, 0);
        }
        __syncthreads();
    }

    // silu(g)*u -> hbuf in A-operand layout (row=token, col=h, k-contiguous)
#pragma unroll
    for (int nt = 0; nt < 8; ++nt) {
#pragma unroll
        for (int r = 0; r < 4; ++r) {
            float g = accG[nt][r], u = accU[nt][r];
            float h = (g / (1.f + expf(-g))) * u;
            int row = w * 16 + quad * 4 + r;    // C/D layout: row=quad*4+reg
            hbuf[row][nt * 16 + m] = (bf16)h;   // col = lane&15
        }
    }
    __syncthreads();

    // ---------- phase 2: down GEMM, M=64, N=1024, K=128 ----------
    float sc_r[4]; int tok_r[4];
#pragma unroll
    for (int r = 0; r < 4; ++r) {
        int row = w * 16 + quad * 4 + r;
        sc_r[r] = ssc[row]; tok_r[r] = stok[row];
    }

    for (int d0 = 0; d0 < DIM; d0 += 128) {
        floatx4 acc[8] = {};
#pragma unroll
        for (int kc = 0; kc < 4; ++kc) {
            bf16x8 af = *(const bf16x8*)(&hbuf[w * 16 + m][kc * 32 + quad * 8]);
            const bf16* dk = dptr + (size_t)(d0 + m) * dstride + kc * 32 + quad * 8;
#pragma unroll
            for (int nt = 0; nt < 8; ++nt) {
                bf16x8 bfr = *(const bf16x8*)(dk + (size_t)nt * 16 * dstride);
                acc[nt] = __builtin_amdgcn_mfma_f32_16x16x32_bf16(af, bfr, acc[nt], 0, 0, 0);
            }
        }
#pragma unroll
        for (int nt = 0; nt < 8; ++nt) {
            int d = d0 + nt * 16 + m;
#pragma unroll
            for (int r = 0; r < 4; ++r) {
                atomicAdd(&out[(size_t)tok_r[r] * DIM + d], acc[nt][r] * sc_r[r]);
            }
        }
    }
}

// ---------------------------------------------------------------- launch
extern "C" void kernel_launch(void* const* d_in, const int* in_sizes, int n_in,
                              void* d_out, int out_size, void* d_ws, size_t ws_size,
                              hipStream_t stream) {
    (void)in_sizes; (void)n_in; (void)out_size; (void)ws_size;
    const float* x   = (const float*)d_in[0];
    const float* rw  = (const float*)d_in[1];
    const float* rb  = (const float*)d_in[2];
    const float* gw  = (const float*)d_in[3];
    const float* uw  = (const float*)d_in[4];
    const float* dw  = (const float*)d_in[5];
    const float* sgw = (const float*)d_in[6];
    const float* suw = (const float*)d_in[7];
    const float* sdw = (const float*)d_in[8];
    float* out = (float*)d_out;

    // workspace layout (~45.1 MiB)
    char* ws = (char*)d_ws;
    size_t o = 0;
    bf16* xb  = (bf16*)(ws + o); o += (size_t)N_TOK * DIM * 2;
    bf16* wgb = (bf16*)(ws + o); o += (size_t)E_R * H_E * DIM * 2;
    bf16* wub = (bf16*)(ws + o); o += (size_t)E_R * H_E * DIM * 2;
    bf16* wdb = (bf16*)(ws + o); o += (size_t)E_R * DIM * H_E * 2;
    bf16* sgb = (bf16*)(ws + o); o += (size_t)HS * DIM * 2;
    bf16* sub = (bf16*)(ws + o); o += (size_t)HS * DIM * 2;
    bf16* sdb = (bf16*)(ws + o); o += (size_t)DIM * HS * 2;
    int*   counts = (int*)(ws + o);   o += 256;
    int*   tlist  = (int*)(ws + o);   o += (size_t)E_R * N_TOK * 4;
    float* slist  = (float*)(ws + o); o += (size_t)E_R * N_TOK * 4;

    hipMemsetAsync(counts, 0, E_R * sizeof(int), stream);
    hipMemsetAsync(out, 0, (size_t)N_TOK * DIM * sizeof(float), stream);

    int nx = N_TOK * DIM;
    cvt_f32_bf16<<<nx / 1024, 256, 0, stream>>>(x, xb, nx);
    int nw = E_R * H_E * DIM;
    cvt_f32_bf16<<<nw / 1024, 256, 0, stream>>>(gw, wgb, nw);
    cvt_f32_bf16<<<nw / 1024, 256, 0, stream>>>(uw, wub, nw);
    cvt_f32_bf16<<<nw / 1024, 256, 0, stream>>>(dw, wdb, nw);
    int ns = HS * DIM;
    cvt_f32_bf16<<<ns / 1024, 256, 0, stream>>>(sgw, sgb, ns);
    cvt_f32_bf16<<<ns / 1024, 256, 0, stream>>>(suw, sub, ns);
    cvt_f32_bf16<<<ns / 1024, 256, 0, stream>>>(sdw, sdb, ns);

    router_kernel<<<N_TOK, 64, 0, stream>>>(x, rw, rb, counts, tlist, slist);

    dim3 grid(N_TOK / TM, NEXP);
    ffn_kernel<<<grid, 256, 0, stream>>>(xb, wgb, wub, wdb, sgb, sub, sdb,
                                         counts, tlist, slist, out);
}

// Round 2
// 795.870 us; speedup vs baseline: 1.4332x; 1.4332x over previous
//
#include <hip/hip_runtime.h>
#include <hip/hip_bf16.h>
#include <math.h>

#define N_TOK 8192
#define DIM   1024
#define E_R   32
#define H_E   128
#define HS    512
#define TOPK  4

typedef __bf16 bf16;
typedef __bf16 bf16x8 __attribute__((ext_vector_type(8)));
typedef float  floatx4 __attribute__((ext_vector_type(4)));

#define MFMA16(a,b,c) __builtin_amdgcn_mfma_f32_16x16x32_bf16(a,b,c,0,0,0)

// ---------------------------------------------------------------- fused convert
// segment block boundaries (2048 elems/block): x:4096, g/u/d:2048 each, sg/su/sd:256 each
__global__ __launch_bounds__(256)
void cvt_all(const float* __restrict__ x, const float* __restrict__ g,
             const float* __restrict__ u, const float* __restrict__ d,
             const float* __restrict__ sg, const float* __restrict__ su,
             const float* __restrict__ sd,
             bf16* __restrict__ xb, bf16* __restrict__ gb, bf16* __restrict__ ub,
             bf16* __restrict__ db, bf16* __restrict__ sgb, bf16* __restrict__ sub,
             bf16* __restrict__ sdb) {
    int b = blockIdx.x;
    const float* s; bf16* o; int lb;
    if      (b < 4096)  { s = x;  o = xb;  lb = b; }
    else if (b < 6144)  { s = g;  o = gb;  lb = b - 4096; }
    else if (b < 8192)  { s = u;  o = ub;  lb = b - 6144; }
    else if (b < 10240) { s = d;  o = db;  lb = b - 8192; }
    else if (b < 10496) { s = sg; o = sgb; lb = b - 10240; }
    else if (b < 10752) { s = su; o = sub; lb = b - 10496; }
    else                { s = sd; o = sdb; lb = b - 10752; }
    size_t i = (size_t)lb * 2048 + threadIdx.x * 8;
    float4 v0 = *(const float4*)(s + i);
    float4 v1 = *(const float4*)(s + i + 4);
    bf16x8 r = {(bf16)v0.x,(bf16)v0.y,(bf16)v0.z,(bf16)v0.w,
                (bf16)v1.x,(bf16)v1.y,(bf16)v1.z,(bf16)v1.w};
    *(bf16x8*)(o + i) = r;
}

// ---------------------------------------------------------------- router (4 tokens/block)
__global__ __launch_bounds__(256)
void router_kernel(const float* __restrict__ x,
                   const float* __restrict__ rw,
                   const float* __restrict__ rb,
                   int* __restrict__ counts,
                   int* __restrict__ tlist,
                   float* __restrict__ slist) {
    int w = threadIdx.x >> 6, lane = threadIdx.x & 63;
    int n = blockIdx.x * 4 + w;
    __shared__ float lds[4][32];

    float xr[16];
#pragma unroll
    for (int i = 0; i < 16; ++i) xr[i] = x[(size_t)n * DIM + lane + i * 64];

    for (int e = 0; e < E_R; ++e) {
        const float* wv = rw + (size_t)e * DIM;
        float p = 0.f;
#pragma unroll
        for (int i = 0; i < 16; ++i) p += xr[i] * wv[lane + i * 64];
#pragma unroll
        for (int off = 32; off; off >>= 1) p += __shfl_xor(p, off);
        if (lane == 0) lds[w][e] = p + rb[e];
    }
    // lane 0 wrote and reads its own wave's slots: no barrier needed
    if (lane == 0) {
        float mx = -1e30f;
        for (int e = 0; e < E_R; ++e) mx = fmaxf(mx, lds[w][e]);
        float se = 0.f;
        for (int e = 0; e < E_R; ++e) { float v = __expf(lds[w][e] - mx); lds[w][e] = v; se += v; }
        float inv = 1.f / se;
        unsigned usedMask = 0;
        int idx[TOPK]; float pv[TOPK]; float psum = 0.f;
        for (int k = 0; k < TOPK; ++k) {
            float best = -1.f; int bi = 0;
            for (int e = 0; e < E_R; ++e)
                if (!((usedMask >> e) & 1) && lds[w][e] > best) { best = lds[w][e]; bi = e; }
            usedMask |= 1u << bi;
            idx[k] = bi; pv[k] = best * inv; psum += pv[k];
        }
        float norm = 1.f / fmaxf(psum, 1e-12f);
        for (int k = 0; k < TOPK; ++k) {
            int e = idx[k];
            int pos = atomicAdd(&counts[e], 1);
            tlist[(size_t)e * N_TOK + pos] = n;
            slist[(size_t)e * N_TOK + pos] = pv[k] * norm;
        }
    }
}

// ---------------------------------------------------------------- work-queue build
__global__ void wq_build(const int* __restrict__ counts, int* __restrict__ items,
                         int* __restrict__ nitems, int* __restrict__ ctr) {
    if (threadIdx.x == 0) {
        int n = 0;
        for (int e = 0; e < E_R; ++e) {
            int nt = (counts[e] + 63) >> 6;
            for (int t = 0; t < nt; ++t) items[n++] = (e << 16) | t;
        }
        *nitems = n; *ctr = 0;
    }
}

// ---------------------------------------------------------------- routed FFN (work-queue)
// 256 threads = 4 waves. Tile: 64 tokens. Phase1: N=256 (gate128|up128), K=1024.
// Wave w: gate/up cols [32w,32w+32). 4 M-groups x (2 gate + 2 up) tiles per wave.
// Phase2: N=1024 in 4 passes, K=128, A-frags held in registers.
__global__ __launch_bounds__(256, 2)
void routed_ffn(const bf16* __restrict__ xb, const bf16* __restrict__ wg,
                const bf16* __restrict__ wu, const bf16* __restrict__ wd,
                const int* __restrict__ counts, const int* __restrict__ tlist,
                const float* __restrict__ slist, const int* __restrict__ items,
                const int* __restrict__ nitems, int* __restrict__ ctr,
                float* __restrict__ out) {
    __shared__ __align__(16) bf16 Ah[64][136];   // union: A-tile (64x128) / hbuf (64x128)
    __shared__ int   stok[64];
    __shared__ float ssc[64];
    __shared__ int   s_item;

    int tid  = threadIdx.x;
    int w    = tid >> 6, lane = tid & 63;
    int m    = lane & 15, quad = lane >> 4;
    int NI   = *nitems;

    for (;;) {
        __syncthreads();                       // protect stok/ssc/Ah across items
        if (tid == 0) s_item = atomicAdd(ctr, 1);
        __syncthreads();
        int it = s_item;
        if (it >= NI) return;
        int e  = items[it] >> 16;
        int t0 = (items[it] & 0xffff) << 6;
        int cnt = counts[e];
        if (tid < 64) {
            int r = t0 + tid;
            bool v = r < cnt;
            stok[tid] = v ? tlist[(size_t)e * N_TOK + r] : 0;
            ssc[tid]  = v ? slist[(size_t)e * N_TOK + r] : 0.f;
        }
        __syncthreads();
        const bf16* gw = wg + (size_t)e * H_E * DIM;
        const bf16* uw = wu + (size_t)e * H_E * DIM;

        floatx4 accG[4][2] = {{{0}}};
        floatx4 accU[4][2] = {{{0}}};

        int arow = tid >> 2;
        int acol = (tid & 3) * 32;
        const bf16* asrc = xb + (size_t)stok[arow] * DIM + acol;

        for (int k0 = 0; k0 < DIM; k0 += 128) {
            bf16x8 s0 = *(const bf16x8*)(asrc + k0);
            bf16x8 s1 = *(const bf16x8*)(asrc + k0 + 8);
            bf16x8 s2 = *(const bf16x8*)(asrc + k0 + 16);
            bf16x8 s3 = *(const bf16x8*)(asrc + k0 + 24);
            *(bf16x8*)&Ah[arow][acol +  0] = s0;
            *(bf16x8*)&Ah[arow][acol +  8] = s1;
            *(bf16x8*)&Ah[arow][acol + 16] = s2;
            *(bf16x8*)&Ah[arow][acol + 24] = s3;
            __syncthreads();
#pragma unroll
            for (int ks = 0; ks < 4; ++ks) {
                bf16x8 a[4];
#pragma unroll
                for (int mg = 0; mg < 4; ++mg)
                    a[mg] = *(const bf16x8*)&Ah[mg * 16 + m][ks * 32 + quad * 8];
                const bf16* gbp = gw + (size_t)(w * 32 + m) * DIM + k0 + ks * 32 + quad * 8;
                const bf16* ubp = uw + (size_t)(w * 32 + m) * DIM + k0 + ks * 32 + quad * 8;
#pragma unroll
                for (int j = 0; j < 2; ++j) {
                    bf16x8 bg = *(const bf16x8*)(gbp + (size_t)j * 16 * DIM);
                    bf16x8 bu = *(const bf16x8*)(ubp + (size_t)j * 16 * DIM);
#pragma unroll
                    for (int mg = 0; mg < 4; ++mg) {
                        accG[mg][j] = MFMA16(a[mg], bg, accG[mg][j]);
                        accU[mg][j] = MFMA16(a[mg], bu, accU[mg][j]);
                    }
                }
            }
            __syncthreads();
        }
        // silu(g)*u -> hbuf (reuse Ah)
#pragma unroll
        for (int mg = 0; mg < 4; ++mg)
#pragma unroll
            for (int j = 0; j < 2; ++j)
#pragma unroll
                for (int r = 0; r < 4; ++r) {
                    float gv = accG[mg][j][r], uv = accU[mg][j][r];
                    float h = gv / (1.f + __expf(-gv)) * uv;
                    Ah[mg * 16 + quad * 4 + r][w * 32 + j * 16 + m] = (bf16)h;
                }
        __syncthreads();
        // phase 2: preload A-frags (whole K=128)
        bf16x8 af[4][4];
#pragma unroll
        for (int mg = 0; mg < 4; ++mg)
#pragma unroll
            for (int ks = 0; ks < 4; ++ks)
                af[mg][ks] = *(const bf16x8*)&Ah[mg * 16 + m][ks * 32 + quad * 8];

        const bf16* dw = wd + (size_t)e * DIM * H_E;
#pragma unroll
        for (int p = 0; p < 4; ++p) {
            floatx4 acc[4][4] = {{{0}}};
#pragma unroll
            for (int ks = 0; ks < 4; ++ks) {
                const bf16* dbp = dw + (size_t)(p * 256 + w * 64 + m) * H_E + ks * 32 + quad * 8;
#pragma unroll
                for (int ng = 0; ng < 4; ++ng) {
                    bf16x8 bd = *(const bf16x8*)(dbp + (size_t)ng * 16 * H_E);
#pragma unroll
                    for (int mg = 0; mg < 4; ++mg)
                        acc[mg][ng] = MFMA16(af[mg][ks], bd, acc[mg][ng]);
                }
            }
#pragma unroll
            for (int mg = 0; mg < 4; ++mg)
#pragma unroll
                for (int r = 0; r < 4; ++r) {
                    int row = mg * 16 + quad * 4 + r;
                    float sc = ssc[row];
                    float* op = out + (size_t)stok[row] * DIM + p * 256 + w * 64 + m;
#pragma unroll
                    for (int ng = 0; ng < 4; ++ng)
                        atomicAdd(op + ng * 16, acc[mg][ng][r] * sc);
                }
        }
    }
}

// ---------------------------------------------------------------- shared expert: up (h -> global)
__global__ __launch_bounds__(256, 2)
void shared_up(const bf16* __restrict__ xb, const bf16* __restrict__ sg,
               const bf16* __restrict__ su, bf16* __restrict__ hs) {
    int t0 = blockIdx.x * 64, c = blockIdx.y;
    const bf16* gw = sg + (size_t)c * H_E * DIM;
    const bf16* uw = su + (size_t)c * H_E * DIM;
    __shared__ __align__(16) bf16 Ah[64][136];

    int tid = threadIdx.x;
    int w = tid >> 6, lane = tid & 63;
    int m = lane & 15, quad = lane >> 4;

    floatx4 accG[4][2] = {{{0}}};
    floatx4 accU[4][2] = {{{0}}};

    int arow = tid >> 2;
    int acol = (tid & 3) * 32;
    const bf16* asrc = xb + (size_t)(t0 + arow) * DIM + acol;

    for (int k0 = 0; k0 < DIM; k0 += 128) {
        bf16x8 s0 = *(const bf16x8*)(asrc + k0);
        bf16x8 s1 = *(const bf16x8*)(asrc + k0 + 8);
        bf16x8 s2 = *(const bf16x8*)(asrc + k0 + 16);
        bf16x8 s3 = *(const bf16x8*)(asrc + k0 + 24);
        *(bf16x8*)&Ah[arow][acol +  0] = s0;
        *(bf16x8*)&Ah[arow][acol +  8] = s1;
        *(bf16x8*)&Ah[arow][acol + 16] = s2;
        *(bf16x8*)&Ah[arow][acol + 24] = s3;
        __syncthreads();
#pragma unroll
        for (int ks = 0; ks < 4; ++ks) {
            bf16x8 a[4];
#pragma unroll
            for (int mg = 0; mg < 4; ++mg)
                a[mg] = *(const bf16x8*)&Ah[mg * 16 + m][ks * 32 + quad * 8];
            const bf16* gbp = gw + (size_t)(w * 32 + m) * DIM + k0 + ks * 32 + quad * 8;
            const bf16* ubp = uw + (size_t)(w * 32 + m) * DIM + k0 + ks * 32 + quad * 8;
#pragma unroll
            for (int j = 0; j < 2; ++j) {
                bf16x8 bg = *(const bf16x8*)(gbp + (size_t)j * 16 * DIM);
                bf16x8 bu = *(const bf16x8*)(ubp + (size_t)j * 16 * DIM);
#pragma unroll
                for (int mg = 0; mg < 4; ++mg) {
                    accG[mg][j] = MFMA16(a[mg], bg, accG[mg][j]);
                    accU[mg][j] = MFMA16(a[mg], bu, accU[mg][j]);
                }
            }
        }
        __syncthreads();
    }
#pragma unroll
    for (int mg = 0; mg < 4; ++mg)
#pragma unroll
        for (int j = 0; j < 2; ++j)
#pragma unroll
            for (int r = 0; r < 4; ++r) {
                float gv = accG[mg][j][r], uv = accU[mg][j][r];
                float h = gv / (1.f + __expf(-gv)) * uv;
                int row = t0 + mg * 16 + quad * 4 + r;
                int col = c * H_E + w * 32 + j * 16 + m;
                hs[(size_t)row * HS + col] = (bf16)h;
            }
}

// ---------------------------------------------------------------- shared expert: down GEMM -> out
__global__ __launch_bounds__(256, 2)
void shared_down(const bf16* __restrict__ hs, const bf16* __restrict__ sd,
                 float* __restrict__ out) {
    int t0 = blockIdx.x * 64;
    int n0 = blockIdx.y * 256;
    __shared__ __align__(16) bf16 Ah[64][136];

    int tid = threadIdx.x;
    int w = tid >> 6, lane = tid & 63;
    int m = lane & 15, quad = lane >> 4;

    floatx4 acc[4][4] = {{{0}}};

    int arow = tid >> 2;
    int acol = (tid & 3) * 32;
    const bf16* asrc = hs + (size_t)(t0 + arow) * HS + acol;

    for (int k0 = 0; k0 < HS; k0 += 128) {
        bf16x8 s0 = *(const bf16x8*)(asrc + k0);
        bf16x8 s1 = *(const bf16x8*)(asrc + k0 + 8);
        bf16x8 s2 = *(const bf16x8*)(asrc + k0 + 16);
        bf16x8 s3 = *(const bf16x8*)(asrc + k0 + 24);
        *(bf16x8*)&Ah[arow][acol +  0] = s0;
        *(bf16x8*)&Ah[arow][acol +  8] = s1;
        *(bf16x8*)&Ah[arow][acol + 16] = s2;
        *(bf16x8*)&Ah[arow][acol + 24] = s3;
        __syncthreads();
#pragma unroll
        for (int ks = 0; ks < 4; ++ks) {
            bf16x8 a[4];
#pragma unroll
            for (int mg = 0; mg < 4; ++mg)
                a[mg] = *(const bf16x8*)&Ah[mg * 16 + m][ks * 32 + quad * 8];
            const bf16* dbp = sd + (size_t)(n0 + w * 64 + m) * HS + k0 + ks * 32 + quad * 8;
#pragma unroll
            for (int ng = 0; ng < 4; ++ng) {
                bf16x8 bd = *(const bf16x8*)(dbp + (size_t)ng * 16 * HS);
#pragma unroll
                for (int mg = 0; mg < 4; ++mg)
                    acc[mg][ng] = MFMA16(a[mg], bd, acc[mg][ng]);
            }
        }
        __syncthreads();
    }
#pragma unroll
    for (int mg = 0; mg < 4; ++mg)
#pragma unroll
        for (int ng = 0; ng < 4; ++ng)
#pragma unroll
            for (int r = 0; r < 4; ++r) {
                int row = t0 + mg * 16 + quad * 4 + r;
                int col = n0 + w * 64 + ng * 16 + m;
                out[(size_t)row * DIM + col] = acc[mg][ng][r];
            }
}

// ---------------------------------------------------------------- launch
extern "C" void kernel_launch(void* const* d_in, const int* in_sizes, int n_in,
                              void* d_out, int out_size, void* d_ws, size_t ws_size,
                              hipStream_t stream) {
    (void)in_sizes; (void)n_in; (void)out_size; (void)ws_size;
    const float* x   = (const float*)d_in[0];
    const float* rw  = (const float*)d_in[1];
    const float* rb  = (const float*)d_in[2];
    const float* gw  = (const float*)d_in[3];
    const float* uw  = (const float*)d_in[4];
    const float* dw  = (const float*)d_in[5];
    const float* sgw = (const float*)d_in[6];
    const float* suw = (const float*)d_in[7];
    const float* sdw = (const float*)d_in[8];
    float* out = (float*)d_out;

    char* ws = (char*)d_ws;
    size_t o = 0;
    bf16* xb  = (bf16*)(ws + o); o += (size_t)N_TOK * DIM * 2;
    bf16* wgb = (bf16*)(ws + o); o += (size_t)E_R * H_E * DIM * 2;
    bf16* wub = (bf16*)(ws + o); o += (size_t)E_R * H_E * DIM * 2;
    bf16* wdb = (bf16*)(ws + o); o += (size_t)E_R * DIM * H_E * 2;
    bf16* sgb = (bf16*)(ws + o); o += (size_t)HS * DIM * 2;
    bf16* sub = (bf16*)(ws + o); o += (size_t)HS * DIM * 2;
    bf16* sdb = (bf16*)(ws + o); o += (size_t)DIM * HS * 2;
    bf16* hs  = (bf16*)(ws + o); o += (size_t)N_TOK * HS * 2;
    int*   counts = (int*)(ws + o);   o += 256;
    int*   tlist  = (int*)(ws + o);   o += (size_t)E_R * N_TOK * 4;
    float* slist  = (float*)(ws + o); o += (size_t)E_R * N_TOK * 4;
    int*   items  = (int*)(ws + o);   o += 4096;
    int*   nitems = (int*)(ws + o);   o += 64;
    int*   ctr    = (int*)(ws + o);   o += 64;

    hipMemsetAsync(counts, 0, E_R * sizeof(int), stream);

    cvt_all<<<11008, 256, 0, stream>>>(x, gw, uw, dw, sgw, suw, sdw,
                                       xb, wgb, wub, wdb, sgb, sub, sdb);
    router_kernel<<<N_TOK / 4, 256, 0, stream>>>(x, rw, rb, counts, tlist, slist);
    wq_build<<<1, 64, 0, stream>>>(counts, items, nitems, ctr);
    shared_up<<<dim3(N_TOK / 64, 4), 256, 0, stream>>>(xb, sgb, sub, hs);
    shared_down<<<dim3(N_TOK / 64, 4), 256, 0, stream>>>(hs, sdb, out);
    routed_ffn<<<512, 256, 0, stream>>>(xb, wgb, wub, wdb, counts, tlist, slist,
                                        items, nitems, ctr, out);
}

// Round 3
// 574.081 us; speedup vs baseline: 1.9868x; 1.3863x over previous
//
#include <hip/hip_runtime.h>
#include <hip/hip_bf16.h>
#include <math.h>

#define N_TOK 8192
#define DIM   1024
#define E_R   32
#define H_E   128
#define HS    512
#define TOPK  4

typedef __bf16 bf16;
typedef __bf16 bf16x8 __attribute__((ext_vector_type(8)));
typedef float  floatx4 __attribute__((ext_vector_type(4)));

#define MFMA16(a,b,c) __builtin_amdgcn_mfma_f32_16x16x32_bf16(a,b,c,0,0,0)

__device__ __forceinline__ void gl_lds16(const bf16* g, bf16* l) {
    __builtin_amdgcn_global_load_lds(
        (const __attribute__((address_space(1))) void*)g,
        (__attribute__((address_space(3))) void*)l, 16, 0, 0);
}

// ---------------------------------------------------------------- fused convert
__global__ __launch_bounds__(256)
void cvt_all(const float* __restrict__ x, const float* __restrict__ g,
             const float* __restrict__ u, const float* __restrict__ d,
             const float* __restrict__ sg, const float* __restrict__ su,
             const float* __restrict__ sd,
             bf16* __restrict__ xb, bf16* __restrict__ gb, bf16* __restrict__ ub,
             bf16* __restrict__ db, bf16* __restrict__ sgb, bf16* __restrict__ sub,
             bf16* __restrict__ sdb) {
    int b = blockIdx.x;
    const float* s; bf16* o; int lb;
    if      (b < 4096)  { s = x;  o = xb;  lb = b; }
    else if (b < 6144)  { s = g;  o = gb;  lb = b - 4096; }
    else if (b < 8192)  { s = u;  o = ub;  lb = b - 6144; }
    else if (b < 10240) { s = d;  o = db;  lb = b - 8192; }
    else if (b < 10496) { s = sg; o = sgb; lb = b - 10240; }
    else if (b < 10752) { s = su; o = sub; lb = b - 10496; }
    else                { s = sd; o = sdb; lb = b - 10752; }
    size_t i = (size_t)lb * 2048 + threadIdx.x * 8;
    float4 v0 = *(const float4*)(s + i);
    float4 v1 = *(const float4*)(s + i + 4);
    bf16x8 r = {(bf16)v0.x,(bf16)v0.y,(bf16)v0.z,(bf16)v0.w,
                (bf16)v1.x,(bf16)v1.y,(bf16)v1.z,(bf16)v1.w};
    *(bf16x8*)(o + i) = r;
}

// ---------------------------------------------------------------- router (4 tokens/block)
__global__ __launch_bounds__(256)
void router_kernel(const float* __restrict__ x,
                   const float* __restrict__ rw,
                   const float* __restrict__ rb,
                   int* __restrict__ counts,
                   int* __restrict__ tlist,
                   float* __restrict__ slist) {
    int w = threadIdx.x >> 6, lane = threadIdx.x & 63;
    int n = blockIdx.x * 4 + w;
    __shared__ float lds[4][32];

    float xr[16];
#pragma unroll
    for (int i = 0; i < 16; ++i) xr[i] = x[(size_t)n * DIM + lane + i * 64];

    for (int e = 0; e < E_R; ++e) {
        const float* wv = rw + (size_t)e * DIM;
        float p = 0.f;
#pragma unroll
        for (int i = 0; i < 16; ++i) p += xr[i] * wv[lane + i * 64];
#pragma unroll
        for (int off = 32; off; off >>= 1) p += __shfl_xor(p, off);
        if (lane == 0) lds[w][e] = p + rb[e];
    }
    if (lane == 0) {
        float mx = -1e30f;
        for (int e = 0; e < E_R; ++e) mx = fmaxf(mx, lds[w][e]);
        float se = 0.f;
        for (int e = 0; e < E_R; ++e) { float v = __expf(lds[w][e] - mx); lds[w][e] = v; se += v; }
        float inv = 1.f / se;
        unsigned usedMask = 0;
        int idx[TOPK]; float pv[TOPK]; float psum = 0.f;
        for (int k = 0; k < TOPK; ++k) {
            float best = -1.f; int bi = 0;
            for (int e = 0; e < E_R; ++e)
                if (!((usedMask >> e) & 1) && lds[w][e] > best) { best = lds[w][e]; bi = e; }
            usedMask |= 1u << bi;
            idx[k] = bi; pv[k] = best * inv; psum += pv[k];
        }
        float norm = 1.f / fmaxf(psum, 1e-12f);
        for (int k = 0; k < TOPK; ++k) {
            int e = idx[k];
            int pos = atomicAdd(&counts[e], 1);
            tlist[(size_t)e * N_TOK + pos] = n;
            slist[(size_t)e * N_TOK + pos] = pv[k] * norm;
        }
    }
}

// ---------------------------------------------------------------- work-queue build
// item = (e<<24) | (t<<16) | rowbase ; 64-row tiles, rowbase = 64-aligned prefix
__global__ void wq_build(const int* __restrict__ counts, int* __restrict__ items,
                         int* __restrict__ nitems) {
    if (threadIdx.x == 0) {
        int n = 0, base = 0;
        for (int e = 0; e < E_R; ++e) {
            int c = counts[e];
            int nt = (c + 63) >> 6;
            for (int t = 0; t < nt; ++t)
                items[n++] = (e << 24) | (t << 16) | (base + t * 64);
            base += nt * 64;
        }
        *nitems = n;
    }
}

// ---------------------------------------------------------------- phase 1
// One block: 64 rows (gathered tokens or identity), computes h = silu(x@g^T)*(x@u^T)
// for 128 hidden cols of its group. b<512: shared chunk; else routed item.
__global__ __launch_bounds__(256, 3)
void phase1(const bf16* __restrict__ xb, const bf16* __restrict__ wg,
            const bf16* __restrict__ wu, const bf16* __restrict__ sg,
            const bf16* __restrict__ su, const int* __restrict__ counts,
            const int* __restrict__ tlist, const int* __restrict__ items,
            const int* __restrict__ nitems,
            bf16* __restrict__ Hg, bf16* __restrict__ Hs) {
    __shared__ __align__(16) bf16 As[64 * 32];
    __shared__ __align__(16) bf16 Bs[256 * 32];

    int b = blockIdx.x;
    const bf16 *gptr, *uptr;
    bf16* hout; int hstride;
    int e, lbase, cnt = 0;
    if (b < 512) {
        int c = b >> 7, t = b & 127;
        gptr = sg + (size_t)c * H_E * DIM;
        uptr = su + (size_t)c * H_E * DIM;
        hout = Hs + (size_t)t * 64 * HS + c * H_E;
        hstride = HS;
        lbase = t * 64;
        e = -1;
    } else {
        int rbk = b - 512;
        if (rbk >= *nitems) return;
        int it = items[rbk];
        e = it >> 24; int t = (it >> 16) & 0xff; int rowbase = it & 0xffff;
        gptr = wg + (size_t)e * H_E * DIM;
        uptr = wu + (size_t)e * H_E * DIM;
        hout = Hg + (size_t)rowbase * H_E;
        hstride = H_E;
        cnt = counts[e];
        lbase = t * 64;
    }

    int tid = threadIdx.x;
    int r = tid >> 2;
    int chunk = (tid & 3) * 8;
    int tok;
    if (e < 0) tok = lbase + r;
    else { int li = lbase + r; if (li >= cnt) li = cnt - 1; tok = tlist[(size_t)e * N_TOK + li]; }
    const bf16* aSrc = xb + (size_t)tok * DIM + chunk;
    const bf16* gSrc = gptr + (size_t)r * DIM + chunk;
    const bf16* uSrc = uptr + (size_t)r * DIM + chunk;
    bf16* aDst = As + tid * 8;
    bf16* bDst = Bs + tid * 8;

    int w = tid >> 6, lane = tid & 63, m = lane & 15, quad = lane >> 4;

    floatx4 aG[4][2] = {{{0}}};
    floatx4 aU[4][2] = {{{0}}};

    for (int k0 = 0; k0 < DIM; k0 += 32) {
        gl_lds16(aSrc + k0, aDst);
        gl_lds16(gSrc + k0, bDst);
        gl_lds16(gSrc + 64 * DIM + k0, bDst + 2048);
        gl_lds16(uSrc + k0, bDst + 4096);
        gl_lds16(uSrc + 64 * DIM + k0, bDst + 6144);
        __syncthreads();
        bf16x8 a[4], bg[2], bu[2];
#pragma unroll
        for (int mg = 0; mg < 4; ++mg)
            a[mg] = *(const bf16x8*)(As + (mg * 16 + m) * 32 + quad * 8);
#pragma unroll
        for (int j = 0; j < 2; ++j) {
            bg[j] = *(const bf16x8*)(Bs + (w * 32 + j * 16 + m) * 32 + quad * 8);
            bu[j] = *(const bf16x8*)(Bs + (128 + w * 32 + j * 16 + m) * 32 + quad * 8);
        }
#pragma unroll
        for (int j = 0; j < 2; ++j)
#pragma unroll
            for (int mg = 0; mg < 4; ++mg) {
                aG[mg][j] = MFMA16(a[mg], bg[j], aG[mg][j]);
                aU[mg][j] = MFMA16(a[mg], bu[j], aU[mg][j]);
            }
        __syncthreads();
    }

#pragma unroll
    for (int mg = 0; mg < 4; ++mg)
#pragma unroll
        for (int j = 0; j < 2; ++j)
#pragma unroll
            for (int r4 = 0; r4 < 4; ++r4) {
                float gv = aG[mg][j][r4], uv = aU[mg][j][r4];
                float h = gv / (1.f + __expf(-gv)) * uv;
                hout[(size_t)(mg * 16 + quad * 4 + r4) * hstride + w * 32 + j * 16 + m] = (bf16)h;
            }
}

// ---------------------------------------------------------------- shared down
// Dense GEMM: out[8192][1024] = Hs[8192][512] @ sd^T ; plain stores (covers all of out)
__global__ __launch_bounds__(256, 3)
void shared_down(const bf16* __restrict__ Hs, const bf16* __restrict__ sd,
                 float* __restrict__ out) {
    __shared__ __align__(16) bf16 As[64 * 32];
    __shared__ __align__(16) bf16 Bs[256 * 32];

    int t0 = blockIdx.x * 64;
    int n0 = blockIdx.y * 256;
    int tid = threadIdx.x;
    int r = tid >> 2, chunk = (tid & 3) * 8;
    const bf16* aSrc = Hs + (size_t)(t0 + r) * HS + chunk;
    const bf16* bSrc = sd + (size_t)(n0 + r) * HS + chunk;
    bf16* aDst = As + tid * 8;
    bf16* bDst = Bs + tid * 8;

    int w = tid >> 6, lane = tid & 63, m = lane & 15, quad = lane >> 4;
    floatx4 acc[4][4] = {{{0}}};

    for (int k0 = 0; k0 < HS; k0 += 32) {
        gl_lds16(aSrc + k0, aDst);
#pragma unroll
        for (int p = 0; p < 4; ++p)
            gl_lds16(bSrc + (size_t)p * 64 * HS + k0, bDst + p * 2048);
        __syncthreads();
        bf16x8 a[4], bb[4];
#pragma unroll
        for (int mg = 0; mg < 4; ++mg)
            a[mg] = *(const bf16x8*)(As + (mg * 16 + m) * 32 + quad * 8);
#pragma unroll
        for (int ng = 0; ng < 4; ++ng)
            bb[ng] = *(const bf16x8*)(Bs + (w * 64 + ng * 16 + m) * 32 + quad * 8);
#pragma unroll
        for (int ng = 0; ng < 4; ++ng)
#pragma unroll
            for (int mg = 0; mg < 4; ++mg)
                acc[mg][ng] = MFMA16(a[mg], bb[ng], acc[mg][ng]);
        __syncthreads();
    }
#pragma unroll
    for (int mg = 0; mg < 4; ++mg)
#pragma unroll
        for (int ng = 0; ng < 4; ++ng)
#pragma unroll
            for (int r4 = 0; r4 < 4; ++r4)
                out[(size_t)(t0 + mg * 16 + quad * 4 + r4) * DIM + n0 + w * 64 + ng * 16 + m]
                    = acc[mg][ng][r4];
}

// ---------------------------------------------------------------- phase 2 (routed down)
// Per (item, col-tile): C[64][256] = Hg_tile @ wd[e]^T ; atomicAdd*score into out
__global__ __launch_bounds__(256, 3)
void phase2(const bf16* __restrict__ Hg, const bf16* __restrict__ wd,
            const int* __restrict__ counts, const int* __restrict__ tlist,
            const float* __restrict__ slist, const int* __restrict__ items,
            const int* __restrict__ nitems, float* __restrict__ out) {
    __shared__ __align__(16) bf16 As[64 * 32];
    __shared__ __align__(16) bf16 Bs[256 * 32];

    int rbk = blockIdx.x;
    if (rbk >= *nitems) return;
    int it = items[rbk];
    int e = it >> 24, t = (it >> 16) & 0xff, rowbase = it & 0xffff;
    int n0 = blockIdx.y * 256;
    int cnt = counts[e];

    int tid = threadIdx.x;
    int r = tid >> 2, chunk = (tid & 3) * 8;
    const bf16* aSrc = Hg + (size_t)(rowbase + r) * H_E + chunk;
    const bf16* bSrc = wd + (size_t)e * DIM * H_E + (size_t)(n0 + r) * H_E + chunk;
    bf16* aDst = As + tid * 8;
    bf16* bDst = Bs + tid * 8;

    int w = tid >> 6, lane = tid & 63, m = lane & 15, quad = lane >> 4;
    floatx4 acc[4][4] = {{{0}}};

    for (int k0 = 0; k0 < H_E; k0 += 32) {
        gl_lds16(aSrc + k0, aDst);
#pragma unroll
        for (int p = 0; p < 4; ++p)
            gl_lds16(bSrc + (size_t)p * 64 * H_E + k0, bDst + p * 2048);
        __syncthreads();
        bf16x8 a[4], bb[4];
#pragma unroll
        for (int mg = 0; mg < 4; ++mg)
            a[mg] = *(const bf16x8*)(As + (mg * 16 + m) * 32 + quad * 8);
#pragma unroll
        for (int ng = 0; ng < 4; ++ng)
            bb[ng] = *(const bf16x8*)(Bs + (w * 64 + ng * 16 + m) * 32 + quad * 8);
#pragma unroll
        for (int ng = 0; ng < 4; ++ng)
#pragma unroll
            for (int mg = 0; mg < 4; ++mg)
                acc[mg][ng] = MFMA16(a[mg], bb[ng], acc[mg][ng]);
        __syncthreads();
    }

    int lb = t * 64;
#pragma unroll
    for (int mg = 0; mg < 4; ++mg)
#pragma unroll
        for (int r4 = 0; r4 < 4; ++r4) {
            int li = lb + mg * 16 + quad * 4 + r4;
            if (li < cnt) {
                int tok  = tlist[(size_t)e * N_TOK + li];
                float sc = slist[(size_t)e * N_TOK + li];
                float* op = out + (size_t)tok * DIM + n0 + w * 64 + m;
#pragma unroll
                for (int ng = 0; ng < 4; ++ng)
                    atomicAdd(op + ng * 16, acc[mg][ng][r4] * sc);
            }
        }
}

// ---------------------------------------------------------------- launch
extern "C" void kernel_launch(void* const* d_in, const int* in_sizes, int n_in,
                              void* d_out, int out_size, void* d_ws, size_t ws_size,
                              hipStream_t stream) {
    (void)in_sizes; (void)n_in; (void)out_size; (void)ws_size;
    const float* x   = (const float*)d_in[0];
    const float* rw  = (const float*)d_in[1];
    const float* rb  = (const float*)d_in[2];
    const float* gw  = (const float*)d_in[3];
    const float* uw  = (const float*)d_in[4];
    const float* dw  = (const float*)d_in[5];
    const float* sgw = (const float*)d_in[6];
    const float* suw = (const float*)d_in[7];
    const float* sdw = (const float*)d_in[8];
    float* out = (float*)d_out;

    char* ws = (char*)d_ws;
    size_t o = 0;
    bf16* xb  = (bf16*)(ws + o); o += (size_t)N_TOK * DIM * 2;
    bf16* wgb = (bf16*)(ws + o); o += (size_t)E_R * H_E * DIM * 2;
    bf16* wub = (bf16*)(ws + o); o += (size_t)E_R * H_E * DIM * 2;
    bf16* wdb = (bf16*)(ws + o); o += (size_t)E_R * DIM * H_E * 2;
    bf16* sgb = (bf16*)(ws + o); o += (size_t)HS * DIM * 2;
    bf16* sub = (bf16*)(ws + o); o += (size_t)HS * DIM * 2;
    bf16* sdb = (bf16*)(ws + o); o += (size_t)DIM * HS * 2;
    bf16* Hg  = (bf16*)(ws + o); o += (size_t)34816 * H_E * 2;
    bf16* Hs  = (bf16*)(ws + o); o += (size_t)N_TOK * HS * 2;
    int*   counts = (int*)(ws + o);   o += 256;
    int*   tlist  = (int*)(ws + o);   o += (size_t)E_R * N_TOK * 4;
    float* slist  = (float*)(ws + o); o += (size_t)E_R * N_TOK * 4;
    int*   items  = (int*)(ws + o);   o += 4096;
    int*   nitems = (int*)(ws + o);   o += 64;

    hipMemsetAsync(counts, 0, E_R * sizeof(int), stream);

    router_kernel<<<N_TOK / 4, 256, 0, stream>>>(x, rw, rb, counts, tlist, slist);
    cvt_all<<<11008, 256, 0, stream>>>(x, gw, uw, dw, sgw, suw, sdw,
                                       xb, wgb, wub, wdb, sgb, sub, sdb);
    wq_build<<<1, 64, 0, stream>>>(counts, items, nitems);
    phase1<<<1056, 256, 0, stream>>>(xb, wgb, wub, sgb, sub, counts, tlist,
                                     items, nitems, Hg, Hs);
    shared_down<<<dim3(N_TOK / 64, 4), 256, 0, stream>>>(Hs, sdb, out);
    phase2<<<dim3(544, 4), 256, 0, stream>>>(Hg, wdb, counts, tlist, slist,
                                             items, nitems, out);
}

// Round 4
// 480.126 us; speedup vs baseline: 2.3756x; 1.1957x over previous
//
#include <hip/hip_runtime.h>
#include <hip/hip_bf16.h>
#include <math.h>

#define N_TOK 8192
#define DIM   1024
#define E_R   32
#define H_E   128
#define HS    512
#define TOPK  4

typedef __bf16 bf16;
typedef __bf16 bf16x8 __attribute__((ext_vector_type(8)));
typedef float  floatx4 __attribute__((ext_vector_type(4)));

#define MFMA16(a,b,c) __builtin_amdgcn_mfma_f32_16x16x32_bf16(a,b,c,0,0,0)

__device__ __forceinline__ void gl_lds16(const bf16* g, bf16* l) {
    __builtin_amdgcn_global_load_lds(
        (const __attribute__((address_space(1))) void*)g,
        (__attribute__((address_space(3))) void*)l, 16, 0, 0);
}

// ---------------------------------------------------------------- fused convert
__global__ __launch_bounds__(256)
void cvt_all(const float* __restrict__ x, const float* __restrict__ g,
             const float* __restrict__ u, const float* __restrict__ d,
             const float* __restrict__ sg, const float* __restrict__ su,
             const float* __restrict__ sd,
             bf16* __restrict__ xb, bf16* __restrict__ gb, bf16* __restrict__ ub,
             bf16* __restrict__ db, bf16* __restrict__ sgb, bf16* __restrict__ sub,
             bf16* __restrict__ sdb) {
    int b = blockIdx.x;
    const float* s; bf16* o; int lb;
    if      (b < 4096)  { s = x;  o = xb;  lb = b; }
    else if (b < 6144)  { s = g;  o = gb;  lb = b - 4096; }
    else if (b < 8192)  { s = u;  o = ub;  lb = b - 6144; }
    else if (b < 10240) { s = d;  o = db;  lb = b - 8192; }
    else if (b < 10496) { s = sg; o = sgb; lb = b - 10240; }
    else if (b < 10752) { s = su; o = sub; lb = b - 10496; }
    else                { s = sd; o = sdb; lb = b - 10752; }
    size_t i = (size_t)lb * 2048 + threadIdx.x * 8;
    float4 v0 = *(const float4*)(s + i);
    float4 v1 = *(const float4*)(s + i + 4);
    bf16x8 r = {(bf16)v0.x,(bf16)v0.y,(bf16)v0.z,(bf16)v0.w,
                (bf16)v1.x,(bf16)v1.y,(bf16)v1.z,(bf16)v1.w};
    *(bf16x8*)(o + i) = r;
}

// ---------------------------------------------------------------- router v2
// Block = 64 tokens x 32 experts, fp32 LDS-tiled mini-GEMM.
// Thread = 4 tokens x 2 experts. K chunked by 64 (x staged in LDS).
__global__ __launch_bounds__(256)
void router_kernel(const float* __restrict__ x,
                   const float* __restrict__ rw,
                   const float* __restrict__ rb,
                   int* __restrict__ counts,
                   int* __restrict__ tlist,
                   float* __restrict__ slist) {
    __shared__ float As[64 * 68];     // x chunk [64 tok][64 k], pad 68
    __shared__ float Ls[64 * 33];     // logits [64 tok][32 e], pad 33

    int t0  = blockIdx.x * 64;
    int tid = threadIdx.x;
    int eg  = tid & 15;               // expert pair group (2 experts)
    int tg  = tid >> 4;               // token quad group (4 tokens)

    int srow = tid >> 2;              // staging: row 0..63
    int scol = (tid & 3) * 16;        // 16 floats per thread

    float acc[4][2] = {{0.f}};
    const float* wp = rw + (size_t)(eg * 2) * DIM;

    for (int kc = 0; kc < DIM; kc += 64) {
        const float* sp = x + (size_t)(t0 + srow) * DIM + kc + scol;
        float4 v0 = *(const float4*)(sp + 0);
        float4 v1 = *(const float4*)(sp + 4);
        float4 v2 = *(const float4*)(sp + 8);
        float4 v3 = *(const float4*)(sp + 12);
        __syncthreads();              // protect As from previous iter readers
        *(float4*)(&As[srow * 68 + scol + 0])  = v0;
        *(float4*)(&As[srow * 68 + scol + 4])  = v1;
        *(float4*)(&As[srow * 68 + scol + 8])  = v2;
        *(float4*)(&As[srow * 68 + scol + 12]) = v3;
        __syncthreads();
#pragma unroll
        for (int k = 0; k < 64; k += 4) {
            float4 w0 = *(const float4*)(wp + kc + k);
            float4 w1 = *(const float4*)(wp + DIM + kc + k);
#pragma unroll
            for (int t = 0; t < 4; ++t) {
                float4 xa = *(const float4*)(&As[(tg * 4 + t) * 68 + k]);
                acc[t][0] += xa.x * w0.x + xa.y * w0.y + xa.z * w0.z + xa.w * w0.w;
                acc[t][1] += xa.x * w1.x + xa.y * w1.y + xa.z * w1.z + xa.w * w1.w;
            }
        }
    }
#pragma unroll
    for (int t = 0; t < 4; ++t) {
        Ls[(tg * 4 + t) * 33 + eg * 2 + 0] = acc[t][0];
        Ls[(tg * 4 + t) * 33 + eg * 2 + 1] = acc[t][1];
    }
    __syncthreads();

    if (tid < 64) {
        int n = t0 + tid;
        float lg[E_R];
        float mx = -1e30f;
#pragma unroll
        for (int e = 0; e < E_R; ++e) {
            lg[e] = Ls[tid * 33 + e] + rb[e];
            mx = fmaxf(mx, lg[e]);
        }
        float se = 0.f;
#pragma unroll
        for (int e = 0; e < E_R; ++e) { float v = __expf(lg[e] - mx); lg[e] = v; se += v; }
        float inv = 1.f / se;
        unsigned usedMask = 0;
        int idx[TOPK]; float pv[TOPK]; float psum = 0.f;
        for (int k = 0; k < TOPK; ++k) {
            float best = -1.f; int bi = 0;
            for (int e = 0; e < E_R; ++e)
                if (!((usedMask >> e) & 1) && lg[e] > best) { best = lg[e]; bi = e; }
            usedMask |= 1u << bi;
            idx[k] = bi; pv[k] = best * inv; psum += pv[k];
        }
        float norm = 1.f / fmaxf(psum, 1e-12f);
        for (int k = 0; k < TOPK; ++k) {
            int e = idx[k];
            int pos = atomicAdd(&counts[e], 1);
            tlist[(size_t)e * N_TOK + pos] = n;
            slist[(size_t)e * N_TOK + pos] = pv[k] * norm;
        }
    }
}

// ---------------------------------------------------------------- work-queue build
// item = (e<<24) | (t<<16) | rowbase ; 64-row tiles, rowbase = 64-aligned prefix
__global__ void wq_build(const int* __restrict__ counts, int* __restrict__ items,
                         int* __restrict__ nitems) {
    if (threadIdx.x == 0) {
        int n = 0, base = 0;
        for (int e = 0; e < E_R; ++e) {
            int c = counts[e];
            int nt = (c + 63) >> 6;
            for (int t = 0; t < nt; ++t)
                items[n++] = (e << 24) | (t << 16) | (base + t * 64);
            base += nt * 64;
        }
        *nitems = n;
    }
}

// ---------------------------------------------------------------- phase 1
__global__ __launch_bounds__(256, 3)
void phase1(const bf16* __restrict__ xb, const bf16* __restrict__ wg,
            const bf16* __restrict__ wu, const bf16* __restrict__ sg,
            const bf16* __restrict__ su, const int* __restrict__ counts,
            const int* __restrict__ tlist, const int* __restrict__ items,
            const int* __restrict__ nitems,
            bf16* __restrict__ Hg, bf16* __restrict__ Hs) {
    __shared__ __align__(16) bf16 As[64 * 32];
    __shared__ __align__(16) bf16 Bs[256 * 32];

    int b = blockIdx.x;
    const bf16 *gptr, *uptr;
    bf16* hout; int hstride;
    int e, lbase, cnt = 0;
    if (b < 512) {
        int c = b >> 7, t = b & 127;
        gptr = sg + (size_t)c * H_E * DIM;
        uptr = su + (size_t)c * H_E * DIM;
        hout = Hs + (size_t)t * 64 * HS + c * H_E;
        hstride = HS;
        lbase = t * 64;
        e = -1;
    } else {
        int rbk = b - 512;
        if (rbk >= *nitems) return;
        int it = items[rbk];
        e = it >> 24; int t = (it >> 16) & 0xff; int rowbase = it & 0xffff;
        gptr = wg + (size_t)e * H_E * DIM;
        uptr = wu + (size_t)e * H_E * DIM;
        hout = Hg + (size_t)rowbase * H_E;
        hstride = H_E;
        cnt = counts[e];
        lbase = t * 64;
    }

    int tid = threadIdx.x;
    int r = tid >> 2;
    int chunk = (tid & 3) * 8;
    int tok;
    if (e < 0) tok = lbase + r;
    else { int li = lbase + r; if (li >= cnt) li = cnt - 1; tok = tlist[(size_t)e * N_TOK + li]; }
    const bf16* aSrc = xb + (size_t)tok * DIM + chunk;
    const bf16* gSrc = gptr + (size_t)r * DIM + chunk;
    const bf16* uSrc = uptr + (size_t)r * DIM + chunk;
    bf16* aDst = As + tid * 8;
    bf16* bDst = Bs + tid * 8;

    int w = tid >> 6, lane = tid & 63, m = lane & 15, quad = lane >> 4;

    floatx4 aG[4][2] = {{{0}}};
    floatx4 aU[4][2] = {{{0}}};

    for (int k0 = 0; k0 < DIM; k0 += 32) {
        gl_lds16(aSrc + k0, aDst);
        gl_lds16(gSrc + k0, bDst);
        gl_lds16(gSrc + 64 * DIM + k0, bDst + 2048);
        gl_lds16(uSrc + k0, bDst + 4096);
        gl_lds16(uSrc + 64 * DIM + k0, bDst + 6144);
        __syncthreads();
        bf16x8 a[4], bg[2], bu[2];
#pragma unroll
        for (int mg = 0; mg < 4; ++mg)
            a[mg] = *(const bf16x8*)(As + (mg * 16 + m) * 32 + quad * 8);
#pragma unroll
        for (int j = 0; j < 2; ++j) {
            bg[j] = *(const bf16x8*)(Bs + (w * 32 + j * 16 + m) * 32 + quad * 8);
            bu[j] = *(const bf16x8*)(Bs + (128 + w * 32 + j * 16 + m) * 32 + quad * 8);
        }
#pragma unroll
        for (int j = 0; j < 2; ++j)
#pragma unroll
            for (int mg = 0; mg < 4; ++mg) {
                aG[mg][j] = MFMA16(a[mg], bg[j], aG[mg][j]);
                aU[mg][j] = MFMA16(a[mg], bu[j], aU[mg][j]);
            }
        __syncthreads();
    }

#pragma unroll
    for (int mg = 0; mg < 4; ++mg)
#pragma unroll
        for (int j = 0; j < 2; ++j)
#pragma unroll
            for (int r4 = 0; r4 < 4; ++r4) {
                float gv = aG[mg][j][r4], uv = aU[mg][j][r4];
                float h = gv / (1.f + __expf(-gv)) * uv;
                hout[(size_t)(mg * 16 + quad * 4 + r4) * hstride + w * 32 + j * 16 + m] = (bf16)h;
            }
}

// ---------------------------------------------------------------- shared down
__global__ __launch_bounds__(256, 3)
void shared_down(const bf16* __restrict__ Hs, const bf16* __restrict__ sd,
                 float* __restrict__ out) {
    __shared__ __align__(16) bf16 As[64 * 32];
    __shared__ __align__(16) bf16 Bs[256 * 32];

    int t0 = blockIdx.x * 64;
    int n0 = blockIdx.y * 256;
    int tid = threadIdx.x;
    int r = tid >> 2, chunk = (tid & 3) * 8;
    const bf16* aSrc = Hs + (size_t)(t0 + r) * HS + chunk;
    const bf16* bSrc = sd + (size_t)(n0 + r) * HS + chunk;
    bf16* aDst = As + tid * 8;
    bf16* bDst = Bs + tid * 8;

    int w = tid >> 6, lane = tid & 63, m = lane & 15, quad = lane >> 4;
    floatx4 acc[4][4] = {{{0}}};

    for (int k0 = 0; k0 < HS; k0 += 32) {
        gl_lds16(aSrc + k0, aDst);
#pragma unroll
        for (int p = 0; p < 4; ++p)
            gl_lds16(bSrc + (size_t)p * 64 * HS + k0, bDst + p * 2048);
        __syncthreads();
        bf16x8 a[4], bb[4];
#pragma unroll
        for (int mg = 0; mg < 4; ++mg)
            a[mg] = *(const bf16x8*)(As + (mg * 16 + m) * 32 + quad * 8);
#pragma unroll
        for (int ng = 0; ng < 4; ++ng)
            bb[ng] = *(const bf16x8*)(Bs + (w * 64 + ng * 16 + m) * 32 + quad * 8);
#pragma unroll
        for (int ng = 0; ng < 4; ++ng)
#pragma unroll
            for (int mg = 0; mg < 4; ++mg)
                acc[mg][ng] = MFMA16(a[mg], bb[ng], acc[mg][ng]);
        __syncthreads();
    }
#pragma unroll
    for (int mg = 0; mg < 4; ++mg)
#pragma unroll
        for (int ng = 0; ng < 4; ++ng)
#pragma unroll
            for (int r4 = 0; r4 < 4; ++r4)
                out[(size_t)(t0 + mg * 16 + quad * 4 + r4) * DIM + n0 + w * 64 + ng * 16 + m]
                    = acc[mg][ng][r4];
}

// ---------------------------------------------------------------- phase 2 (routed down)
__global__ __launch_bounds__(256, 3)
void phase2(const bf16* __restrict__ Hg, const bf16* __restrict__ wd,
            const int* __restrict__ counts, const int* __restrict__ tlist,
            const float* __restrict__ slist, const int* __restrict__ items,
            const int* __restrict__ nitems, float* __restrict__ out) {
    __shared__ __align__(16) bf16 As[64 * 32];
    __shared__ __align__(16) bf16 Bs[256 * 32];

    int rbk = blockIdx.x;
    if (rbk >= *nitems) return;
    int it = items[rbk];
    int e = it >> 24, t = (it >> 16) & 0xff, rowbase = it & 0xffff;
    int n0 = blockIdx.y * 256;
    int cnt = counts[e];

    int tid = threadIdx.x;
    int r = tid >> 2, chunk = (tid & 3) * 8;
    const bf16* aSrc = Hg + (size_t)(rowbase + r) * H_E + chunk;
    const bf16* bSrc = wd + (size_t)e * DIM * H_E + (size_t)(n0 + r) * H_E + chunk;
    bf16* aDst = As + tid * 8;
    bf16* bDst = Bs + tid * 8;

    int w = tid >> 6, lane = tid & 63, m = lane & 15, quad = lane >> 4;
    floatx4 acc[4][4] = {{{0}}};

    for (int k0 = 0; k0 < H_E; k0 += 32) {
        gl_lds16(aSrc + k0, aDst);
#pragma unroll
        for (int p = 0; p < 4; ++p)
            gl_lds16(bSrc + (size_t)p * 64 * H_E + k0, bDst + p * 2048);
        __syncthreads();
        bf16x8 a[4], bb[4];
#pragma unroll
        for (int mg = 0; mg < 4; ++mg)
            a[mg] = *(const bf16x8*)(As + (mg * 16 + m) * 32 + quad * 8);
#pragma unroll
        for (int ng = 0; ng < 4; ++ng)
            bb[ng] = *(const bf16x8*)(Bs + (w * 64 + ng * 16 + m) * 32 + quad * 8);
#pragma unroll
        for (int ng = 0; ng < 4; ++ng)
#pragma unroll
            for (int mg = 0; mg < 4; ++mg)
                acc[mg][ng] = MFMA16(a[mg], bb[ng], acc[mg][ng]);
        __syncthreads();
    }

    int lb = t * 64;
#pragma unroll
    for (int mg = 0; mg < 4; ++mg)
#pragma unroll
        for (int r4 = 0; r4 < 4; ++r4) {
            int li = lb + mg * 16 + quad * 4 + r4;
            if (li < cnt) {
                int tok  = tlist[(size_t)e * N_TOK + li];
                float sc = slist[(size_t)e * N_TOK + li];
                float* op = out + (size_t)tok * DIM + n0 + w * 64 + m;
#pragma unroll
                for (int ng = 0; ng < 4; ++ng)
                    atomicAdd(op + ng * 16, acc[mg][ng][r4] * sc);
            }
        }
}

// ---------------------------------------------------------------- launch
extern "C" void kernel_launch(void* const* d_in, const int* in_sizes, int n_in,
                              void* d_out, int out_size, void* d_ws, size_t ws_size,
                              hipStream_t stream) {
    (void)in_sizes; (void)n_in; (void)out_size; (void)ws_size;
    const float* x   = (const float*)d_in[0];
    const float* rw  = (const float*)d_in[1];
    const float* rb  = (const float*)d_in[2];
    const float* gw  = (const float*)d_in[3];
    const float* uw  = (const float*)d_in[4];
    const float* dw  = (const float*)d_in[5];
    const float* sgw = (const float*)d_in[6];
    const float* suw = (const float*)d_in[7];
    const float* sdw = (const float*)d_in[8];
    float* out = (float*)d_out;

    char* ws = (char*)d_ws;
    size_t o = 0;
    bf16* xb  = (bf16*)(ws + o); o += (size_t)N_TOK * DIM * 2;
    bf16* wgb = (bf16*)(ws + o); o += (size_t)E_R * H_E * DIM * 2;
    bf16* wub = (bf16*)(ws + o); o += (size_t)E_R * H_E * DIM * 2;
    bf16* wdb = (bf16*)(ws + o); o += (size_t)E_R * DIM * H_E * 2;
    bf16* sgb = (bf16*)(ws + o); o += (size_t)HS * DIM * 2;
    bf16* sub = (bf16*)(ws + o); o += (size_t)HS * DIM * 2;
    bf16* sdb = (bf16*)(ws + o); o += (size_t)DIM * HS * 2;
    bf16* Hg  = (bf16*)(ws + o); o += (size_t)34816 * H_E * 2;
    bf16* Hs  = (bf16*)(ws + o); o += (size_t)N_TOK * HS * 2;
    int*   counts = (int*)(ws + o);   o += 256;
    int*   tlist  = (int*)(ws + o);   o += (size_t)E_R * N_TOK * 4;
    float* slist  = (float*)(ws + o); o += (size_t)E_R * N_TOK * 4;
    int*   items  = (int*)(ws + o);   o += 4096;
    int*   nitems = (int*)(ws + o);   o += 64;

    hipMemsetAsync(counts, 0, E_R * sizeof(int), stream);

    router_kernel<<<N_TOK / 64, 256, 0, stream>>>(x, rw, rb, counts, tlist, slist);
    cvt_all<<<11008, 256, 0, stream>>>(x, gw, uw, dw, sgw, suw, sdw,
                                       xb, wgb, wub, wdb, sgb, sub, sdb);
    wq_build<<<1, 64, 0, stream>>>(counts, items, nitems);
    phase1<<<1056, 256, 0, stream>>>(xb, wgb, wub, sgb, sub, counts, tlist,
                                     items, nitems, Hg, Hs);
    shared_down<<<dim3(N_TOK / 64, 4), 256, 0, stream>>>(Hs, sdb, out);
    phase2<<<dim3(544, 4), 256, 0, stream>>>(Hg, wdb, counts, tlist, slist,
                                             items, nitems, out);
}

// Round 5
// 427.986 us; speedup vs baseline: 2.6651x; 1.1218x over previous
//
#include <hip/hip_runtime.h>
#include <hip/hip_bf16.h>
#include <math.h>

#define N_TOK 8192
#define DIM   1024
#define E_R   32
#define H_E   128
#define HS    512
#define TOPK  4
#define RKS   8            // router K-splits
#define RKL   (DIM / RKS)  // 128 K per split

typedef __bf16 bf16;
typedef __bf16 bf16x8 __attribute__((ext_vector_type(8)));
typedef float  floatx4 __attribute__((ext_vector_type(4)));

#define MFMA16(a,b,c) __builtin_amdgcn_mfma_f32_16x16x32_bf16(a,b,c,0,0,0)

__device__ __forceinline__ void gl_lds16(const bf16* g, bf16* l) {
    __builtin_amdgcn_global_load_lds(
        (const __attribute__((address_space(1))) void*)g,
        (__attribute__((address_space(3))) void*)l, 16, 0, 0);
}

// ---------------------------------------------------------------- fused convert
__global__ __launch_bounds__(256)
void cvt_all(const float* __restrict__ x, const float* __restrict__ g,
             const float* __restrict__ u, const float* __restrict__ d,
             const float* __restrict__ sg, const float* __restrict__ su,
             const float* __restrict__ sd,
             bf16* __restrict__ xb, bf16* __restrict__ gb, bf16* __restrict__ ub,
             bf16* __restrict__ db, bf16* __restrict__ sgb, bf16* __restrict__ sub,
             bf16* __restrict__ sdb) {
    int b = blockIdx.x;
    const float* s; bf16* o; int lb;
    if      (b < 4096)  { s = x;  o = xb;  lb = b; }
    else if (b < 6144)  { s = g;  o = gb;  lb = b - 4096; }
    else if (b < 8192)  { s = u;  o = ub;  lb = b - 6144; }
    else if (b < 10240) { s = d;  o = db;  lb = b - 8192; }
    else if (b < 10496) { s = sg; o = sgb; lb = b - 10240; }
    else if (b < 10752) { s = su; o = sub; lb = b - 10496; }
    else                { s = sd; o = sdb; lb = b - 10752; }
    size_t i = (size_t)lb * 2048 + threadIdx.x * 8;
    float4 v0 = *(const float4*)(s + i);
    float4 v1 = *(const float4*)(s + i + 4);
    bf16x8 r = {(bf16)v0.x,(bf16)v0.y,(bf16)v0.z,(bf16)v0.w,
                (bf16)v1.x,(bf16)v1.y,(bf16)v1.z,(bf16)v1.w};
    *(bf16x8*)(o + i) = r;
}

// ---------------------------------------------------------------- router v3: K-split GEMM
// grid (128 token-tiles, 8 K-splits). Thread = 2 tokens x 4 experts, K=128.
// All loads direct from global (broadcast-coalesced, L1-resident).
__global__ __launch_bounds__(256)
void router_gemm(const float* __restrict__ x, const float* __restrict__ rw,
                 float* __restrict__ partial) {
    int tid = threadIdx.x;
    int eg  = tid & 7;          // expert quad: e = eg*4 .. eg*4+3
    int tg  = tid >> 3;         // token pair: t0+tg*2, +1
    int t0  = blockIdx.x * 64;
    int kb  = blockIdx.y * RKL;

    const float* wp = rw + (size_t)(eg * 4) * DIM + kb;
    const float* xp = x + (size_t)(t0 + tg * 2) * DIM + kb;

    float acc[2][4] = {{0.f}};
#pragma unroll 8
    for (int k = 0; k < RKL; k += 4) {
        float4 w0 = *(const float4*)(wp + 0 * DIM + k);
        float4 w1 = *(const float4*)(wp + 1 * DIM + k);
        float4 w2 = *(const float4*)(wp + 2 * DIM + k);
        float4 w3 = *(const float4*)(wp + 3 * DIM + k);
#pragma unroll
        for (int t = 0; t < 2; ++t) {
            float4 xa = *(const float4*)(xp + (size_t)t * DIM + k);
            acc[t][0] += xa.x * w0.x + xa.y * w0.y + xa.z * w0.z + xa.w * w0.w;
            acc[t][1] += xa.x * w1.x + xa.y * w1.y + xa.z * w1.z + xa.w * w1.w;
            acc[t][2] += xa.x * w2.x + xa.y * w2.y + xa.z * w2.z + xa.w * w2.w;
            acc[t][3] += xa.x * w3.x + xa.y * w3.y + xa.z * w3.z + xa.w * w3.w;
        }
    }
#pragma unroll
    for (int t = 0; t < 2; ++t) {
        floatx4 v = { acc[t][0], acc[t][1], acc[t][2], acc[t][3] };
        *(floatx4*)(&partial[((size_t)blockIdx.y * N_TOK + t0 + tg * 2 + t) * 32 + eg * 4]) = v;
    }
}

// ---------------------------------------------------------------- router finalize
// thread = token: sum 8 partials, softmax, top-4, scatter (LDS-aggregated counts)
__global__ __launch_bounds__(256)
void router_fin(const float* __restrict__ partial, const float* __restrict__ rb,
                int* __restrict__ counts, int* __restrict__ tlist,
                float* __restrict__ slist) {
    __shared__ int lcnt[E_R];
    __shared__ int gbase[E_R];
    int tid = threadIdx.x;
    int n = blockIdx.x * 256 + tid;
    if (tid < E_R) lcnt[tid] = 0;
    __syncthreads();

    float lg[E_R];
#pragma unroll
    for (int e4 = 0; e4 < E_R; e4 += 4) {
        floatx4 s = {0.f, 0.f, 0.f, 0.f};
#pragma unroll
        for (int ks = 0; ks < RKS; ++ks)
            s += *(const floatx4*)(&partial[((size_t)ks * N_TOK + n) * 32 + e4]);
        lg[e4 + 0] = s[0] + rb[e4 + 0];
        lg[e4 + 1] = s[1] + rb[e4 + 1];
        lg[e4 + 2] = s[2] + rb[e4 + 2];
        lg[e4 + 3] = s[3] + rb[e4 + 3];
    }
    float mx = -1e30f;
#pragma unroll
    for (int e = 0; e < E_R; ++e) mx = fmaxf(mx, lg[e]);
    float se = 0.f;
#pragma unroll
    for (int e = 0; e < E_R; ++e) { float v = __expf(lg[e] - mx); lg[e] = v; se += v; }
    float inv = 1.f / se;

    unsigned usedMask = 0;
    int idx[TOPK]; float pv[TOPK]; int lpos[TOPK]; float psum = 0.f;
    for (int k = 0; k < TOPK; ++k) {
        float best = -1.f; int bi = 0;
        for (int e = 0; e < E_R; ++e)
            if (!((usedMask >> e) & 1) && lg[e] > best) { best = lg[e]; bi = e; }
        usedMask |= 1u << bi;
        idx[k] = bi; pv[k] = best * inv; psum += pv[k];
    }
    float norm = 1.f / fmaxf(psum, 1e-12f);
#pragma unroll
    for (int k = 0; k < TOPK; ++k)
        lpos[k] = atomicAdd(&lcnt[idx[k]], 1);
    __syncthreads();
    if (tid < E_R) gbase[tid] = atomicAdd(&counts[tid], lcnt[tid]);
    __syncthreads();
#pragma unroll
    for (int k = 0; k < TOPK; ++k) {
        int e = idx[k];
        int pos = gbase[e] + lpos[k];
        tlist[(size_t)e * N_TOK + pos] = n;
        slist[(size_t)e * N_TOK + pos] = pv[k] * norm;
    }
}

// ---------------------------------------------------------------- work-queue build
__global__ void wq_build(const int* __restrict__ counts, int* __restrict__ items,
                         int* __restrict__ nitems) {
    if (threadIdx.x == 0) {
        int n = 0, base = 0;
        for (int e = 0; e < E_R; ++e) {
            int c = counts[e];
            int nt = (c + 63) >> 6;
            for (int t = 0; t < nt; ++t)
                items[n++] = (e << 24) | (t << 16) | (base + t * 64);
            base += nt * 64;
        }
        *nitems = n;
    }
}

// ---------------------------------------------------------------- phase 1
__global__ __launch_bounds__(256, 3)
void phase1(const bf16* __restrict__ xb, const bf16* __restrict__ wg,
            const bf16* __restrict__ wu, const bf16* __restrict__ sg,
            const bf16* __restrict__ su, const int* __restrict__ counts,
            const int* __restrict__ tlist, const int* __restrict__ items,
            const int* __restrict__ nitems,
            bf16* __restrict__ Hg, bf16* __restrict__ Hs) {
    __shared__ __align__(16) bf16 As[64 * 32];
    __shared__ __align__(16) bf16 Bs[256 * 32];

    int b = blockIdx.x;
    const bf16 *gptr, *uptr;
    bf16* hout; int hstride;
    int e, lbase, cnt = 0;
    if (b < 512) {
        int c = b >> 7, t = b & 127;
        gptr = sg + (size_t)c * H_E * DIM;
        uptr = su + (size_t)c * H_E * DIM;
        hout = Hs + (size_t)t * 64 * HS + c * H_E;
        hstride = HS;
        lbase = t * 64;
        e = -1;
    } else {
        int rbk = b - 512;
        if (rbk >= *nitems) return;
        int it = items[rbk];
        e = it >> 24; int t = (it >> 16) & 0xff; int rowbase = it & 0xffff;
        gptr = wg + (size_t)e * H_E * DIM;
        uptr = wu + (size_t)e * H_E * DIM;
        hout = Hg + (size_t)rowbase * H_E;
        hstride = H_E;
        cnt = counts[e];
        lbase = t * 64;
    }

    int tid = threadIdx.x;
    int r = tid >> 2;
    int chunk = (tid & 3) * 8;
    int tok;
    if (e < 0) tok = lbase + r;
    else { int li = lbase + r; if (li >= cnt) li = cnt - 1; tok = tlist[(size_t)e * N_TOK + li]; }
    const bf16* aSrc = xb + (size_t)tok * DIM + chunk;
    const bf16* gSrc = gptr + (size_t)r * DIM + chunk;
    const bf16* uSrc = uptr + (size_t)r * DIM + chunk;
    bf16* aDst = As + tid * 8;
    bf16* bDst = Bs + tid * 8;

    int w = tid >> 6, lane = tid & 63, m = lane & 15, quad = lane >> 4;

    floatx4 aG[4][2] = {{{0}}};
    floatx4 aU[4][2] = {{{0}}};

    for (int k0 = 0; k0 < DIM; k0 += 32) {
        gl_lds16(aSrc + k0, aDst);
        gl_lds16(gSrc + k0, bDst);
        gl_lds16(gSrc + 64 * DIM + k0, bDst + 2048);
        gl_lds16(uSrc + k0, bDst + 4096);
        gl_lds16(uSrc + 64 * DIM + k0, bDst + 6144);
        __syncthreads();
        bf16x8 a[4], bg[2], bu[2];
#pragma unroll
        for (int mg = 0; mg < 4; ++mg)
            a[mg] = *(const bf16x8*)(As + (mg * 16 + m) * 32 + quad * 8);
#pragma unroll
        for (int j = 0; j < 2; ++j) {
            bg[j] = *(const bf16x8*)(Bs + (w * 32 + j * 16 + m) * 32 + quad * 8);
            bu[j] = *(const bf16x8*)(Bs + (128 + w * 32 + j * 16 + m) * 32 + quad * 8);
        }
#pragma unroll
        for (int j = 0; j < 2; ++j)
#pragma unroll
            for (int mg = 0; mg < 4; ++mg) {
                aG[mg][j] = MFMA16(a[mg], bg[j], aG[mg][j]);
                aU[mg][j] = MFMA16(a[mg], bu[j], aU[mg][j]);
            }
        __syncthreads();
    }

#pragma unroll
    for (int mg = 0; mg < 4; ++mg)
#pragma unroll
        for (int j = 0; j < 2; ++j)
#pragma unroll
            for (int r4 = 0; r4 < 4; ++r4) {
                float gv = aG[mg][j][r4], uv = aU[mg][j][r4];
                float h = gv / (1.f + __expf(-gv)) * uv;
                hout[(size_t)(mg * 16 + quad * 4 + r4) * hstride + w * 32 + j * 16 + m] = (bf16)h;
            }
}

// ---------------------------------------------------------------- shared down
__global__ __launch_bounds__(256, 3)
void shared_down(const bf16* __restrict__ Hs, const bf16* __restrict__ sd,
                 float* __restrict__ out) {
    __shared__ __align__(16) bf16 As[64 * 32];
    __shared__ __align__(16) bf16 Bs[256 * 32];

    int t0 = blockIdx.x * 64;
    int n0 = blockIdx.y * 256;
    int tid = threadIdx.x;
    int r = tid >> 2, chunk = (tid & 3) * 8;
    const bf16* aSrc = Hs + (size_t)(t0 + r) * HS + chunk;
    const bf16* bSrc = sd + (size_t)(n0 + r) * HS + chunk;
    bf16* aDst = As + tid * 8;
    bf16* bDst = Bs + tid * 8;

    int w = tid >> 6, lane = tid & 63, m = lane & 15, quad = lane >> 4;
    floatx4 acc[4][4] = {{{0}}};

    for (int k0 = 0; k0 < HS; k0 += 32) {
        gl_lds16(aSrc + k0, aDst);
#pragma unroll
        for (int p = 0; p < 4; ++p)
            gl_lds16(bSrc + (size_t)p * 64 * HS + k0, bDst + p * 2048);
        __syncthreads();
        bf16x8 a[4], bb[4];
#pragma unroll
        for (int mg = 0; mg < 4; ++mg)
            a[mg] = *(const bf16x8*)(As + (mg * 16 + m) * 32 + quad * 8);
#pragma unroll
        for (int ng = 0; ng < 4; ++ng)
            bb[ng] = *(const bf16x8*)(Bs + (w * 64 + ng * 16 + m) * 32 + quad * 8);
#pragma unroll
        for (int ng = 0; ng < 4; ++ng)
#pragma unroll
            for (int mg = 0; mg < 4; ++mg)
                acc[mg][ng] = MFMA16(a[mg], bb[ng], acc[mg][ng]);
        __syncthreads();
    }
#pragma unroll
    for (int mg = 0; mg < 4; ++mg)
#pragma unroll
        for (int ng = 0; ng < 4; ++ng)
#pragma unroll
            for (int r4 = 0; r4 < 4; ++r4)
                out[(size_t)(t0 + mg * 16 + quad * 4 + r4) * DIM + n0 + w * 64 + ng * 16 + m]
                    = acc[mg][ng][r4];
}

// ---------------------------------------------------------------- phase 2 (routed down)
__global__ __launch_bounds__(256, 3)
void phase2(const bf16* __restrict__ Hg, const bf16* __restrict__ wd,
            const int* __restrict__ counts, const int* __restrict__ tlist,
            const float* __restrict__ slist, const int* __restrict__ items,
            const int* __restrict__ nitems, float* __restrict__ out) {
    __shared__ __align__(16) bf16 As[64 * 32];
    __shared__ __align__(16) bf16 Bs[256 * 32];

    int rbk = blockIdx.x;
    if (rbk >= *nitems) return;
    int it = items[rbk];
    int e = it >> 24, t = (it >> 16) & 0xff, rowbase = it & 0xffff;
    int n0 = blockIdx.y * 256;
    int cnt = counts[e];

    int tid = threadIdx.x;
    int r = tid >> 2, chunk = (tid & 3) * 8;
    const bf16* aSrc = Hg + (size_t)(rowbase + r) * H_E + chunk;
    const bf16* bSrc = wd + (size_t)e * DIM * H_E + (size_t)(n0 + r) * H_E + chunk;
    bf16* aDst = As + tid * 8;
    bf16* bDst = Bs + tid * 8;

    int w = tid >> 6, lane = tid & 63, m = lane & 15, quad = lane >> 4;
    floatx4 acc[4][4] = {{{0}}};

    for (int k0 = 0; k0 < H_E; k0 += 32) {
        gl_lds16(aSrc + k0, aDst);
#pragma unroll
        for (int p = 0; p < 4; ++p)
            gl_lds16(bSrc + (size_t)p * 64 * H_E + k0, bDst + p * 2048);
        __syncthreads();
        bf16x8 a[4], bb[4];
#pragma unroll
        for (int mg = 0; mg < 4; ++mg)
            a[mg] = *(const bf16x8*)(As + (mg * 16 + m) * 32 + quad * 8);
#pragma unroll
        for (int ng = 0; ng < 4; ++ng)
            bb[ng] = *(const bf16x8*)(Bs + (w * 64 + ng * 16 + m) * 32 + quad * 8);
#pragma unroll
        for (int ng = 0; ng < 4; ++ng)
#pragma unroll
            for (int mg = 0; mg < 4; ++mg)
                acc[mg][ng] = MFMA16(a[mg], bb[ng], acc[mg][ng]);
        __syncthreads();
    }

    int lb = t * 64;
#pragma unroll
    for (int mg = 0; mg < 4; ++mg)
#pragma unroll
        for (int r4 = 0; r4 < 4; ++r4) {
            int li = lb + mg * 16 + quad * 4 + r4;
            if (li < cnt) {
                int tok  = tlist[(size_t)e * N_TOK + li];
                float sc = slist[(size_t)e * N_TOK + li];
                float* op = out + (size_t)tok * DIM + n0 + w * 64 + m;
#pragma unroll
                for (int ng = 0; ng < 4; ++ng)
                    atomicAdd(op + ng * 16, acc[mg][ng][r4] * sc);
            }
        }
}

// ---------------------------------------------------------------- launch
extern "C" void kernel_launch(void* const* d_in, const int* in_sizes, int n_in,
                              void* d_out, int out_size, void* d_ws, size_t ws_size,
                              hipStream_t stream) {
    (void)in_sizes; (void)n_in; (void)out_size; (void)ws_size;
    const float* x   = (const float*)d_in[0];
    const float* rw  = (const float*)d_in[1];
    const float* rb  = (const float*)d_in[2];
    const float* gw  = (const float*)d_in[3];
    const float* uw  = (const float*)d_in[4];
    const float* dw  = (const float*)d_in[5];
    const float* sgw = (const float*)d_in[6];
    const float* suw = (const float*)d_in[7];
    const float* sdw = (const float*)d_in[8];
    float* out = (float*)d_out;

    char* ws = (char*)d_ws;
    size_t o = 0;
    bf16* xb  = (bf16*)(ws + o); o += (size_t)N_TOK * DIM * 2;
    bf16* wgb = (bf16*)(ws + o); o += (size_t)E_R * H_E * DIM * 2;
    bf16* wub = (bf16*)(ws + o); o += (size_t)E_R * H_E * DIM * 2;
    bf16* wdb = (bf16*)(ws + o); o += (size_t)E_R * DIM * H_E * 2;
    bf16* sgb = (bf16*)(ws + o); o += (size_t)HS * DIM * 2;
    bf16* sub = (bf16*)(ws + o); o += (size_t)HS * DIM * 2;
    bf16* sdb = (bf16*)(ws + o); o += (size_t)DIM * HS * 2;
    bf16* Hg  = (bf16*)(ws + o); o += (size_t)34816 * H_E * 2;
    bf16* Hs  = (bf16*)(ws + o); o += (size_t)N_TOK * HS * 2;
    float* partial = (float*)(ws + o); o += (size_t)RKS * N_TOK * 32 * 4;
    int*   counts = (int*)(ws + o);   o += 256;
    int*   tlist  = (int*)(ws + o);   o += (size_t)E_R * N_TOK * 4;
    float* slist  = (float*)(ws + o); o += (size_t)E_R * N_TOK * 4;
    int*   items  = (int*)(ws + o);   o += 4096;
    int*   nitems = (int*)(ws + o);   o += 64;

    hipMemsetAsync(counts, 0, E_R * sizeof(int), stream);

    router_gemm<<<dim3(N_TOK / 64, RKS), 256, 0, stream>>>(x, rw, partial);
    router_fin<<<N_TOK / 256, 256, 0, stream>>>(partial, rb, counts, tlist, slist);
    cvt_all<<<11008, 256, 0, stream>>>(x, gw, uw, dw, sgw, suw, sdw,
                                       xb, wgb, wub, wdb, sgb, sub, sdb);
    wq_build<<<1, 64, 0, stream>>>(counts, items, nitems);
    phase1<<<1056, 256, 0, stream>>>(xb, wgb, wub, sgb, sub, counts, tlist,
                                     items, nitems, Hg, Hs);
    shared_down<<<dim3(N_TOK / 64, 4), 256, 0, stream>>>(Hs, sdb, out);
    phase2<<<dim3(544, 4), 256, 0, stream>>>(Hg, wdb, counts, tlist, slist,
                                             items, nitems, out);
}

// Round 6
// 359.532 us; speedup vs baseline: 3.1725x; 1.1904x over previous
//
#include <hip/hip_runtime.h>
#include <hip/hip_bf16.h>
#include <math.h>

#define N_TOK 8192
#define DIM   1024
#define E_R   32
#define H_E   128
#define HS    512
#define TOPK  4
#define RKS   8            // router K-splits
#define RKL   (DIM / RKS)  // 128 K per split
#define MAXSLOT 34816      // max padded slot rows (8192*4 + 32*63, rounded)

typedef __bf16 bf16;
typedef __bf16 bf16x8 __attribute__((ext_vector_type(8)));
typedef float  floatx4 __attribute__((ext_vector_type(4)));

#define MFMA16(a,b,c) __builtin_amdgcn_mfma_f32_16x16x32_bf16(a,b,c,0,0,0)

__device__ __forceinline__ void gl_lds16(const bf16* g, bf16* l) {
    __builtin_amdgcn_global_load_lds(
        (const __attribute__((address_space(1))) void*)g,
        (__attribute__((address_space(3))) void*)l, 16, 0, 0);
}

// ---------------------------------------------------------------- fused convert
__global__ __launch_bounds__(256)
void cvt_all(const float* __restrict__ x, const float* __restrict__ g,
             const float* __restrict__ u, const float* __restrict__ d,
             const float* __restrict__ sg, const float* __restrict__ su,
             const float* __restrict__ sd,
             bf16* __restrict__ xb, bf16* __restrict__ gb, bf16* __restrict__ ub,
             bf16* __restrict__ db, bf16* __restrict__ sgb, bf16* __restrict__ sub,
             bf16* __restrict__ sdb) {
    int b = blockIdx.x;
    const float* s; bf16* o; int lb;
    if      (b < 4096)  { s = x;  o = xb;  lb = b; }
    else if (b < 6144)  { s = g;  o = gb;  lb = b - 4096; }
    else if (b < 8192)  { s = u;  o = ub;  lb = b - 6144; }
    else if (b < 10240) { s = d;  o = db;  lb = b - 8192; }
    else if (b < 10496) { s = sg; o = sgb; lb = b - 10240; }
    else if (b < 10752) { s = su; o = sub; lb = b - 10496; }
    else                { s = sd; o = sdb; lb = b - 10752; }
    size_t i = (size_t)lb * 2048 + threadIdx.x * 8;
    float4 v0 = *(const float4*)(s + i);
    float4 v1 = *(const float4*)(s + i + 4);
    bf16x8 r = {(bf16)v0.x,(bf16)v0.y,(bf16)v0.z,(bf16)v0.w,
                (bf16)v1.x,(bf16)v1.y,(bf16)v1.z,(bf16)v1.w};
    *(bf16x8*)(o + i) = r;
}

// ---------------------------------------------------------------- router: K-split GEMM
__global__ __launch_bounds__(256)
void router_gemm(const float* __restrict__ x, const float* __restrict__ rw,
                 float* __restrict__ partial) {
    int tid = threadIdx.x;
    int eg  = tid & 7;
    int tg  = tid >> 3;
    int t0  = blockIdx.x * 64;
    int kb  = blockIdx.y * RKL;

    const float* wp = rw + (size_t)(eg * 4) * DIM + kb;
    const float* xp = x + (size_t)(t0 + tg * 2) * DIM + kb;

    float acc[2][4] = {{0.f}};
#pragma unroll 8
    for (int k = 0; k < RKL; k += 4) {
        float4 w0 = *(const float4*)(wp + 0 * DIM + k);
        float4 w1 = *(const float4*)(wp + 1 * DIM + k);
        float4 w2 = *(const float4*)(wp + 2 * DIM + k);
        float4 w3 = *(const float4*)(wp + 3 * DIM + k);
#pragma unroll
        for (int t = 0; t < 2; ++t) {
            float4 xa = *(const float4*)(xp + (size_t)t * DIM + k);
            acc[t][0] += xa.x * w0.x + xa.y * w0.y + xa.z * w0.z + xa.w * w0.w;
            acc[t][1] += xa.x * w1.x + xa.y * w1.y + xa.z * w1.z + xa.w * w1.w;
            acc[t][2] += xa.x * w2.x + xa.y * w2.y + xa.z * w2.z + xa.w * w2.w;
            acc[t][3] += xa.x * w3.x + xa.y * w3.y + xa.z * w3.z + xa.w * w3.w;
        }
    }
#pragma unroll
    for (int t = 0; t < 2; ++t) {
        floatx4 v = { acc[t][0], acc[t][1], acc[t][2], acc[t][3] };
        *(floatx4*)(&partial[((size_t)blockIdx.y * N_TOK + t0 + tg * 2 + t) * 32 + eg * 4]) = v;
    }
}

// ---------------------------------------------------------------- router finalize
// + records tok2slot[n][k] = (e<<16) | pos  (final position within expert list)
__global__ __launch_bounds__(256)
void router_fin(const float* __restrict__ partial, const float* __restrict__ rb,
                int* __restrict__ counts, int* __restrict__ tlist,
                float* __restrict__ slist, int* __restrict__ tok2slot) {
    __shared__ int lcnt[E_R];
    __shared__ int gbase[E_R];
    int tid = threadIdx.x;
    int n = blockIdx.x * 256 + tid;
    if (tid < E_R) lcnt[tid] = 0;
    __syncthreads();

    float lg[E_R];
#pragma unroll
    for (int e4 = 0; e4 < E_R; e4 += 4) {
        floatx4 s = {0.f, 0.f, 0.f, 0.f};
#pragma unroll
        for (int ks = 0; ks < RKS; ++ks)
            s += *(const floatx4*)(&partial[((size_t)ks * N_TOK + n) * 32 + e4]);
        lg[e4 + 0] = s[0] + rb[e4 + 0];
        lg[e4 + 1] = s[1] + rb[e4 + 1];
        lg[e4 + 2] = s[2] + rb[e4 + 2];
        lg[e4 + 3] = s[3] + rb[e4 + 3];
    }
    float mx = -1e30f;
#pragma unroll
    for (int e = 0; e < E_R; ++e) mx = fmaxf(mx, lg[e]);
    float se = 0.f;
#pragma unroll
    for (int e = 0; e < E_R; ++e) { float v = __expf(lg[e] - mx); lg[e] = v; se += v; }
    float inv = 1.f / se;

    unsigned usedMask = 0;
    int idx[TOPK]; float pv[TOPK]; int lpos[TOPK]; float psum = 0.f;
    for (int k = 0; k < TOPK; ++k) {
        float best = -1.f; int bi = 0;
        for (int e = 0; e < E_R; ++e)
            if (!((usedMask >> e) & 1) && lg[e] > best) { best = lg[e]; bi = e; }
        usedMask |= 1u << bi;
        idx[k] = bi; pv[k] = best * inv; psum += pv[k];
    }
    float norm = 1.f / fmaxf(psum, 1e-12f);
#pragma unroll
    for (int k = 0; k < TOPK; ++k)
        lpos[k] = atomicAdd(&lcnt[idx[k]], 1);
    __syncthreads();
    if (tid < E_R) gbase[tid] = atomicAdd(&counts[tid], lcnt[tid]);
    __syncthreads();
#pragma unroll
    for (int k = 0; k < TOPK; ++k) {
        int e = idx[k];
        int pos = gbase[e] + lpos[k];
        tlist[(size_t)e * N_TOK + pos] = n;
        slist[(size_t)e * N_TOK + pos] = pv[k] * norm;
        tok2slot[(size_t)n * 4 + k] = (e << 16) | pos;
    }
}

// ---------------------------------------------------------------- work-queue build
// Also emits expbase[e] = 64-aligned slot-region start per expert.
__global__ void wq_build(const int* __restrict__ counts, int* __restrict__ items,
                         int* __restrict__ nitems, int* __restrict__ expbase) {
    if (threadIdx.x == 0) {
        int n = 0, base = 0;
        for (int e = 0; e < E_R; ++e) {
            int c = counts[e];
            expbase[e] = base;
            int nt = (c + 63) >> 6;
            for (int t = 0; t < nt; ++t)
                items[n++] = (e << 24) | (t << 16) | (base + t * 64);
            base += nt * 64;
        }
        *nitems = n;
    }
}

// ---------------------------------------------------------------- phase 1
__global__ __launch_bounds__(256, 3)
void phase1(const bf16* __restrict__ xb, const bf16* __restrict__ wg,
            const bf16* __restrict__ wu, const bf16* __restrict__ sg,
            const bf16* __restrict__ su, const int* __restrict__ counts,
            const int* __restrict__ tlist, const int* __restrict__ items,
            const int* __restrict__ nitems,
            bf16* __restrict__ Hg, bf16* __restrict__ Hs) {
    __shared__ __align__(16) bf16 As[64 * 32];
    __shared__ __align__(16) bf16 Bs[256 * 32];

    int b = blockIdx.x;
    const bf16 *gptr, *uptr;
    bf16* hout; int hstride;
    int e, lbase, cnt = 0;
    if (b < 512) {
        int c = b >> 7, t = b & 127;
        gptr = sg + (size_t)c * H_E * DIM;
        uptr = su + (size_t)c * H_E * DIM;
        hout = Hs + (size_t)t * 64 * HS + c * H_E;
        hstride = HS;
        lbase = t * 64;
        e = -1;
    } else {
        int rbk = b - 512;
        if (rbk >= *nitems) return;
        int it = items[rbk];
        e = it >> 24; int t = (it >> 16) & 0xff; int rowbase = it & 0xffff;
        gptr = wg + (size_t)e * H_E * DIM;
        uptr = wu + (size_t)e * H_E * DIM;
        hout = Hg + (size_t)rowbase * H_E;
        hstride = H_E;
        cnt = counts[e];
        lbase = t * 64;
    }

    int tid = threadIdx.x;
    int r = tid >> 2;
    int chunk = (tid & 3) * 8;
    int tok;
    if (e < 0) tok = lbase + r;
    else { int li = lbase + r; if (li >= cnt) li = cnt - 1; tok = tlist[(size_t)e * N_TOK + li]; }
    const bf16* aSrc = xb + (size_t)tok * DIM + chunk;
    const bf16* gSrc = gptr + (size_t)r * DIM + chunk;
    const bf16* uSrc = uptr + (size_t)r * DIM + chunk;
    bf16* aDst = As + tid * 8;
    bf16* bDst = Bs + tid * 8;

    int w = tid >> 6, lane = tid & 63, m = lane & 15, quad = lane >> 4;

    floatx4 aG[4][2] = {{{0}}};
    floatx4 aU[4][2] = {{{0}}};

    for (int k0 = 0; k0 < DIM; k0 += 32) {
        gl_lds16(aSrc + k0, aDst);
        gl_lds16(gSrc + k0, bDst);
        gl_lds16(gSrc + 64 * DIM + k0, bDst + 2048);
        gl_lds16(uSrc + k0, bDst + 4096);
        gl_lds16(uSrc + 64 * DIM + k0, bDst + 6144);
        __syncthreads();
        bf16x8 a[4], bg[2], bu[2];
#pragma unroll
        for (int mg = 0; mg < 4; ++mg)
            a[mg] = *(const bf16x8*)(As + (mg * 16 + m) * 32 + quad * 8);
#pragma unroll
        for (int j = 0; j < 2; ++j) {
            bg[j] = *(const bf16x8*)(Bs + (w * 32 + j * 16 + m) * 32 + quad * 8);
            bu[j] = *(const bf16x8*)(Bs + (128 + w * 32 + j * 16 + m) * 32 + quad * 8);
        }
#pragma unroll
        for (int j = 0; j < 2; ++j)
#pragma unroll
            for (int mg = 0; mg < 4; ++mg) {
                aG[mg][j] = MFMA16(a[mg], bg[j], aG[mg][j]);
                aU[mg][j] = MFMA16(a[mg], bu[j], aU[mg][j]);
            }
        __syncthreads();
    }

#pragma unroll
    for (int mg = 0; mg < 4; ++mg)
#pragma unroll
        for (int j = 0; j < 2; ++j)
#pragma unroll
            for (int r4 = 0; r4 < 4; ++r4) {
                float gv = aG[mg][j][r4], uv = aU[mg][j][r4];
                float h = gv / (1.f + __expf(-gv)) * uv;
                hout[(size_t)(mg * 16 + quad * 4 + r4) * hstride + w * 32 + j * 16 + m] = (bf16)h;
            }
}

// ---------------------------------------------------------------- phase 2 (routed down)
// C[64][256] = Hg_tile @ wd[e]^T, scaled by score, PLAIN bf16 stores to Od[slot][1024]
__global__ __launch_bounds__(256, 3)
void phase2(const bf16* __restrict__ Hg, const bf16* __restrict__ wd,
            const int* __restrict__ counts, const float* __restrict__ slist,
            const int* __restrict__ items, const int* __restrict__ nitems,
            bf16* __restrict__ Od) {
    __shared__ __align__(16) bf16 As[64 * 32];
    __shared__ __align__(16) bf16 Bs[256 * 32];
    __shared__ float ssc[64];

    int rbk = blockIdx.x;
    if (rbk >= *nitems) return;
    int it = items[rbk];
    int e = it >> 24, t = (it >> 16) & 0xff, rowbase = it & 0xffff;
    int n0 = blockIdx.y * 256;
    int cnt = counts[e];

    int tid = threadIdx.x;
    if (tid < 64) {
        int li = t * 64 + tid;
        ssc[tid] = (li < cnt) ? slist[(size_t)e * N_TOK + li] : 0.f;
    }

    int r = tid >> 2, chunk = (tid & 3) * 8;
    const bf16* aSrc = Hg + (size_t)(rowbase + r) * H_E + chunk;
    const bf16* bSrc = wd + (size_t)e * DIM * H_E + (size_t)(n0 + r) * H_E + chunk;
    bf16* aDst = As + tid * 8;
    bf16* bDst = Bs + tid * 8;

    int w = tid >> 6, lane = tid & 63, m = lane & 15, quad = lane >> 4;
    floatx4 acc[4][4] = {{{0}}};

    for (int k0 = 0; k0 < H_E; k0 += 32) {
        gl_lds16(aSrc + k0, aDst);
#pragma unroll
        for (int p = 0; p < 4; ++p)
            gl_lds16(bSrc + (size_t)p * 64 * H_E + k0, bDst + p * 2048);
        __syncthreads();
        bf16x8 a[4], bb[4];
#pragma unroll
        for (int mg = 0; mg < 4; ++mg)
            a[mg] = *(const bf16x8*)(As + (mg * 16 + m) * 32 + quad * 8);
#pragma unroll
        for (int ng = 0; ng < 4; ++ng)
            bb[ng] = *(const bf16x8*)(Bs + (w * 64 + ng * 16 + m) * 32 + quad * 8);
#pragma unroll
        for (int ng = 0; ng < 4; ++ng)
#pragma unroll
            for (int mg = 0; mg < 4; ++mg)
                acc[mg][ng] = MFMA16(a[mg], bb[ng], acc[mg][ng]);
        __syncthreads();
    }

#pragma unroll
    for (int mg = 0; mg < 4; ++mg)
#pragma unroll
        for (int r4 = 0; r4 < 4; ++r4) {
            int row = mg * 16 + quad * 4 + r4;
            float sc = ssc[row];
            bf16* op = Od + (size_t)(rowbase + row) * DIM + n0 + w * 64 + m;
#pragma unroll
            for (int ng = 0; ng < 4; ++ng)
                op[ng * 16] = (bf16)(acc[mg][ng][r4] * sc);
        }
}

// ---------------------------------------------------------------- shared down + routed reduce
// out[t][n] = (Hs[t] @ sd^T)[n] + sum_k Od[slot_k(t)][n]
__global__ __launch_bounds__(256, 3)
void shared_down(const bf16* __restrict__ Hs, const bf16* __restrict__ sd,
                 const bf16* __restrict__ Od, const int* __restrict__ tok2slot,
                 const int* __restrict__ expbase, float* __restrict__ out) {
    __shared__ __align__(16) bf16 As[64 * 32];
    __shared__ __align__(16) bf16 Bs[256 * 32];
    __shared__ int srow[64][4];

    int t0 = blockIdx.x * 64;
    int n0 = blockIdx.y * 256;
    int tid = threadIdx.x;

    if (tid < 64) {
        const int* t2s = tok2slot + (size_t)(t0 + tid) * 4;
#pragma unroll
        for (int k = 0; k < 4; ++k) {
            int v = t2s[k];
            srow[tid][k] = expbase[v >> 16] + (v & 0xffff);
        }
    }

    int r = tid >> 2, chunk = (tid & 3) * 8;
    const bf16* aSrc = Hs + (size_t)(t0 + r) * HS + chunk;
    const bf16* bSrc = sd + (size_t)(n0 + r) * HS + chunk;
    bf16* aDst = As + tid * 8;
    bf16* bDst = Bs + tid * 8;

    int w = tid >> 6, lane = tid & 63, m = lane & 15, quad = lane >> 4;
    floatx4 acc[4][4] = {{{0}}};

    for (int k0 = 0; k0 < HS; k0 += 32) {
        gl_lds16(aSrc + k0, aDst);
#pragma unroll
        for (int p = 0; p < 4; ++p)
            gl_lds16(bSrc + (size_t)p * 64 * HS + k0, bDst + p * 2048);
        __syncthreads();
        bf16x8 a[4], bb[4];
#pragma unroll
        for (int mg = 0; mg < 4; ++mg)
            a[mg] = *(const bf16x8*)(As + (mg * 16 + m) * 32 + quad * 8);
#pragma unroll
        for (int ng = 0; ng < 4; ++ng)
            bb[ng] = *(const bf16x8*)(Bs + (w * 64 + ng * 16 + m) * 32 + quad * 8);
#pragma unroll
        for (int ng = 0; ng < 4; ++ng)
#pragma unroll
            for (int mg = 0; mg < 4; ++mg)
                acc[mg][ng] = MFMA16(a[mg], bb[ng], acc[mg][ng]);
        __syncthreads();
    }

#pragma unroll
    for (int mg = 0; mg < 4; ++mg)
#pragma unroll
        for (int r4 = 0; r4 < 4; ++r4) {
            int rl = mg * 16 + quad * 4 + r4;
            size_t r0 = (size_t)srow[rl][0] * DIM;
            size_t r1 = (size_t)srow[rl][1] * DIM;
            size_t r2 = (size_t)srow[rl][2] * DIM;
            size_t r3 = (size_t)srow[rl][3] * DIM;
            float* op = out + (size_t)(t0 + rl) * DIM + n0 + w * 64 + m;
#pragma unroll
            for (int ng = 0; ng < 4; ++ng) {
                int col = n0 + w * 64 + ng * 16 + m;
                float v = acc[mg][ng][r4]
                        + (float)Od[r0 + col] + (float)Od[r1 + col]
                        + (float)Od[r2 + col] + (float)Od[r3 + col];
                op[ng * 16] = v;
            }
        }
}

// ---------------------------------------------------------------- launch
extern "C" void kernel_launch(void* const* d_in, const int* in_sizes, int n_in,
                              void* d_out, int out_size, void* d_ws, size_t ws_size,
                              hipStream_t stream) {
    (void)in_sizes; (void)n_in; (void)out_size; (void)ws_size;
    const float* x   = (const float*)d_in[0];
    const float* rw  = (const float*)d_in[1];
    const float* rb  = (const float*)d_in[2];
    const float* gw  = (const float*)d_in[3];
    const float* uw  = (const float*)d_in[4];
    const float* dw  = (const float*)d_in[5];
    const float* sgw = (const float*)d_in[6];
    const float* suw = (const float*)d_in[7];
    const float* sdw = (const float*)d_in[8];
    float* out = (float*)d_out;

    char* ws = (char*)d_ws;
    size_t o = 0;
    bf16* xb  = (bf16*)(ws + o); o += (size_t)N_TOK * DIM * 2;
    bf16* wgb = (bf16*)(ws + o); o += (size_t)E_R * H_E * DIM * 2;
    bf16* wub = (bf16*)(ws + o); o += (size_t)E_R * H_E * DIM * 2;
    bf16* wdb = (bf16*)(ws + o); o += (size_t)E_R * DIM * H_E * 2;
    bf16* sgb = (bf16*)(ws + o); o += (size_t)HS * DIM * 2;
    bf16* sub = (bf16*)(ws + o); o += (size_t)HS * DIM * 2;
    bf16* sdb = (bf16*)(ws + o); o += (size_t)DIM * HS * 2;
    bf16* Hg  = (bf16*)(ws + o); o += (size_t)MAXSLOT * H_E * 2;
    bf16* Hs  = (bf16*)(ws + o); o += (size_t)N_TOK * HS * 2;
    bf16* Od  = (bf16*)(ws + o); o += (size_t)MAXSLOT * DIM * 2;
    float* partial = (float*)(ws + o); o += (size_t)RKS * N_TOK * 32 * 4;
    int*   counts = (int*)(ws + o);   o += 256;
    int*   tlist  = (int*)(ws + o);   o += (size_t)E_R * N_TOK * 4;
    float* slist  = (float*)(ws + o); o += (size_t)E_R * N_TOK * 4;
    int*   tok2slot = (int*)(ws + o); o += (size_t)N_TOK * 4 * 4;
    int*   items  = (int*)(ws + o);   o += 4096;
    int*   nitems = (int*)(ws + o);   o += 64;
    int*   expbase = (int*)(ws + o);  o += 256;

    hipMemsetAsync(counts, 0, E_R * sizeof(int), stream);

    router_gemm<<<dim3(N_TOK / 64, RKS), 256, 0, stream>>>(x, rw, partial);
    router_fin<<<N_TOK / 256, 256, 0, stream>>>(partial, rb, counts, tlist, slist,
                                                tok2slot);
    cvt_all<<<11008, 256, 0, stream>>>(x, gw, uw, dw, sgw, suw, sdw,
                                       xb, wgb, wub, wdb, sgb, sub, sdb);
    wq_build<<<1, 64, 0, stream>>>(counts, items, nitems, expbase);
    phase1<<<1056, 256, 0, stream>>>(xb, wgb, wub, sgb, sub, counts, tlist,
                                     items, nitems, Hg, Hs);
    phase2<<<dim3(544, 4), 256, 0, stream>>>(Hg, wdb, counts, slist,
                                             items, nitems, Od);
    shared_down<<<dim3(N_TOK / 64, 4), 256, 0, stream>>>(Hs, sdb, Od, tok2slot,
                                                         expbase, out);
}

// Round 7
// 311.286 us; speedup vs baseline: 3.6642x; 1.1550x over previous
//
#include <hip/hip_runtime.h>
#include <hip/hip_bf16.h>
#include <math.h>

#define N_TOK 8192
#define DIM   1024
#define E_R   32
#define H_E   128
#define HS    512
#define TOPK  4
#define RKS   8            // router K-splits
#define RKL   (DIM / RKS)  // 128 K per split
#define MAXSLOT 34816

typedef __bf16 bf16;
typedef __bf16 bf16x8 __attribute__((ext_vector_type(8)));
typedef float  floatx4 __attribute__((ext_vector_type(4)));

#define MFMA16(a,b,c) __builtin_amdgcn_mfma_f32_16x16x32_bf16(a,b,c,0,0,0)

__device__ __forceinline__ void gl_lds16(const bf16* g, bf16* l) {
    __builtin_amdgcn_global_load_lds(
        (const __attribute__((address_space(1))) void*)g,
        (__attribute__((address_space(3))) void*)l, 16, 0, 0);
}

// ---------------------------------------------------------------- fused convert
__global__ __launch_bounds__(256)
void cvt_all(const float* __restrict__ x, const float* __restrict__ g,
             const float* __restrict__ u, const float* __restrict__ d,
             const float* __restrict__ sg, const float* __restrict__ su,
             const float* __restrict__ sd,
             bf16* __restrict__ xb, bf16* __restrict__ gb, bf16* __restrict__ ub,
             bf16* __restrict__ db, bf16* __restrict__ sgb, bf16* __restrict__ sub,
             bf16* __restrict__ sdb) {
    int b = blockIdx.x;
    const float* s; bf16* o; int lb;
    if      (b < 4096)  { s = x;  o = xb;  lb = b; }
    else if (b < 6144)  { s = g;  o = gb;  lb = b - 4096; }
    else if (b < 8192)  { s = u;  o = ub;  lb = b - 6144; }
    else if (b < 10240) { s = d;  o = db;  lb = b - 8192; }
    else if (b < 10496) { s = sg; o = sgb; lb = b - 10240; }
    else if (b < 10752) { s = su; o = sub; lb = b - 10496; }
    else                { s = sd; o = sdb; lb = b - 10752; }
    size_t i = (size_t)lb * 2048 + threadIdx.x * 8;
    float4 v0 = *(const float4*)(s + i);
    float4 v1 = *(const float4*)(s + i + 4);
    bf16x8 r = {(bf16)v0.x,(bf16)v0.y,(bf16)v0.z,(bf16)v0.w,
                (bf16)v1.x,(bf16)v1.y,(bf16)v1.z,(bf16)v1.w};
    *(bf16x8*)(o + i) = r;
}

// ---------------------------------------------------------------- router v4: LDS-staged K-split GEMM
// grid (128 tiles, 8 ksplits). One-shot staging: Xs[64][128]pad132 + Wt[128][32]
// (weights transposed: float4 read = 4 experts at one k, conflict-free broadcast).
__global__ __launch_bounds__(256)
void router_gemm(const float* __restrict__ x, const float* __restrict__ rw,
                 float* __restrict__ partial) {
    __shared__ float Xs[64 * 132];
    __shared__ float Wt[128 * 32];
    int tid = threadIdx.x;
    int t0  = blockIdx.x * 64;
    int kb  = blockIdx.y * RKL;

    // stage x tile (coalesced float4, padded rows)
#pragma unroll
    for (int j = 0; j < 8; ++j) {
        int flat = j * 1024 + tid * 4;
        int row = flat >> 7, col = flat & 127;
        float4 v = *(const float4*)(x + (size_t)(t0 + row) * DIM + kb + col);
        *(float4*)(&Xs[row * 132 + col]) = v;
    }
    // stage weights transposed: Wt[k][e]
    {
        int e = tid >> 3, kq = (tid & 7) * 16;
        const float* wp = rw + (size_t)e * DIM + kb + kq;
#pragma unroll
        for (int i = 0; i < 16; i += 4) {
            float4 v = *(const float4*)(wp + i);
            Wt[(kq + i + 0) * 32 + e] = v.x;
            Wt[(kq + i + 1) * 32 + e] = v.y;
            Wt[(kq + i + 2) * 32 + e] = v.z;
            Wt[(kq + i + 3) * 32 + e] = v.w;
        }
    }
    __syncthreads();

    int eg = tid & 7, tg = tid >> 3;
    float acc[2][4] = {{0.f}};
#pragma unroll 4
    for (int k = 0; k < RKL; k += 4) {
        float4 xa0 = *(const float4*)(&Xs[(tg * 2 + 0) * 132 + k]);
        float4 xa1 = *(const float4*)(&Xs[(tg * 2 + 1) * 132 + k]);
#pragma unroll
        for (int kk = 0; kk < 4; ++kk) {
            float4 w = *(const float4*)(&Wt[(k + kk) * 32 + eg * 4]);
            float x0 = (&xa0.x)[kk], x1 = (&xa1.x)[kk];
            acc[0][0] += x0 * w.x; acc[0][1] += x0 * w.y;
            acc[0][2] += x0 * w.z; acc[0][3] += x0 * w.w;
            acc[1][0] += x1 * w.x; acc[1][1] += x1 * w.y;
            acc[1][2] += x1 * w.z; acc[1][3] += x1 * w.w;
        }
    }
#pragma unroll
    for (int t = 0; t < 2; ++t) {
        floatx4 v = { acc[t][0], acc[t][1], acc[t][2], acc[t][3] };
        *(floatx4*)(&partial[((size_t)blockIdx.y * N_TOK + t0 + tg * 2 + t) * 32 + eg * 4]) = v;
    }
}

// ---------------------------------------------------------------- router finalize
__global__ __launch_bounds__(256)
void router_fin(const float* __restrict__ partial, const float* __restrict__ rb,
                int* __restrict__ counts, int* __restrict__ tlist,
                float* __restrict__ slist, int* __restrict__ tok2slot) {
    __shared__ int lcnt[E_R];
    __shared__ int gbase[E_R];
    int tid = threadIdx.x;
    int n = blockIdx.x * 256 + tid;
    if (tid < E_R) lcnt[tid] = 0;
    __syncthreads();

    float lg[E_R];
#pragma unroll
    for (int e4 = 0; e4 < E_R; e4 += 4) {
        floatx4 s = {0.f, 0.f, 0.f, 0.f};
#pragma unroll
        for (int ks = 0; ks < RKS; ++ks)
            s += *(const floatx4*)(&partial[((size_t)ks * N_TOK + n) * 32 + e4]);
        lg[e4 + 0] = s[0] + rb[e4 + 0];
        lg[e4 + 1] = s[1] + rb[e4 + 1];
        lg[e4 + 2] = s[2] + rb[e4 + 2];
        lg[e4 + 3] = s[3] + rb[e4 + 3];
    }
    float mx = -1e30f;
#pragma unroll
    for (int e = 0; e < E_R; ++e) mx = fmaxf(mx, lg[e]);
    float se = 0.f;
#pragma unroll
    for (int e = 0; e < E_R; ++e) { float v = __expf(lg[e] - mx); lg[e] = v; se += v; }
    float inv = 1.f / se;

    unsigned usedMask = 0;
    int idx[TOPK]; float pv[TOPK]; int lpos[TOPK]; float psum = 0.f;
    for (int k = 0; k < TOPK; ++k) {
        float best = -1.f; int bi = 0;
        for (int e = 0; e < E_R; ++e)
            if (!((usedMask >> e) & 1) && lg[e] > best) { best = lg[e]; bi = e; }
        usedMask |= 1u << bi;
        idx[k] = bi; pv[k] = best * inv; psum += pv[k];
    }
    float norm = 1.f / fmaxf(psum, 1e-12f);
#pragma unroll
    for (int k = 0; k < TOPK; ++k)
        lpos[k] = atomicAdd(&lcnt[idx[k]], 1);
    __syncthreads();
    if (tid < E_R) gbase[tid] = atomicAdd(&counts[tid], lcnt[tid]);
    __syncthreads();
#pragma unroll
    for (int k = 0; k < TOPK; ++k) {
        int e = idx[k];
        int pos = gbase[e] + lpos[k];
        tlist[(size_t)e * N_TOK + pos] = n;
        slist[(size_t)e * N_TOK + pos] = pv[k] * norm;
        tok2slot[(size_t)n * 4 + k] = (e << 16) | pos;
    }
}

// ---------------------------------------------------------------- work-queue build
__global__ void wq_build(const int* __restrict__ counts, int* __restrict__ items,
                         int* __restrict__ nitems, int* __restrict__ expbase) {
    if (threadIdx.x == 0) {
        int n = 0, base = 0;
        for (int e = 0; e < E_R; ++e) {
            int c = counts[e];
            expbase[e] = base;
            int nt = (c + 63) >> 6;
            for (int t = 0; t < nt; ++t)
                items[n++] = (e << 24) | (t << 16) | (base + t * 64);
            base += nt * 64;
        }
        *nitems = n;
    }
}

// ---------------------------------------------------------------- phase 1
__global__ __launch_bounds__(256, 3)
void phase1(const bf16* __restrict__ xb, const bf16* __restrict__ wg,
            const bf16* __restrict__ wu, const bf16* __restrict__ sg,
            const bf16* __restrict__ su, const int* __restrict__ counts,
            const int* __restrict__ tlist, const int* __restrict__ items,
            const int* __restrict__ nitems,
            bf16* __restrict__ Hg, bf16* __restrict__ Hs) {
    __shared__ __align__(16) bf16 As[64 * 32];
    __shared__ __align__(16) bf16 Bs[256 * 32];

    int b = blockIdx.x;
    const bf16 *gptr, *uptr;
    bf16* hout; int hstride;
    int e, lbase, cnt = 0;
    if (b < 512) {
        int c = b >> 7, t = b & 127;
        gptr = sg + (size_t)c * H_E * DIM;
        uptr = su + (size_t)c * H_E * DIM;
        hout = Hs + (size_t)t * 64 * HS + c * H_E;
        hstride = HS;
        lbase = t * 64;
        e = -1;
    } else {
        int rbk = b - 512;
        if (rbk >= *nitems) return;
        int it = items[rbk];
        e = it >> 24; int t = (it >> 16) & 0xff; int rowbase = it & 0xffff;
        gptr = wg + (size_t)e * H_E * DIM;
        uptr = wu + (size_t)e * H_E * DIM;
        hout = Hg + (size_t)rowbase * H_E;
        hstride = H_E;
        cnt = counts[e];
        lbase = t * 64;
    }

    int tid = threadIdx.x;
    int r = tid >> 2;
    int chunk = (tid & 3) * 8;
    int tok;
    if (e < 0) tok = lbase + r;
    else { int li = lbase + r; if (li >= cnt) li = cnt - 1; tok = tlist[(size_t)e * N_TOK + li]; }
    const bf16* aSrc = xb + (size_t)tok * DIM + chunk;
    const bf16* gSrc = gptr + (size_t)r * DIM + chunk;
    const bf16* uSrc = uptr + (size_t)r * DIM + chunk;
    bf16* aDst = As + tid * 8;
    bf16* bDst = Bs + tid * 8;

    int w = tid >> 6, lane = tid & 63, m = lane & 15, quad = lane >> 4;

    floatx4 aG[4][2] = {{{0}}};
    floatx4 aU[4][2] = {{{0}}};

    for (int k0 = 0; k0 < DIM; k0 += 32) {
        gl_lds16(aSrc + k0, aDst);
        gl_lds16(gSrc + k0, bDst);
        gl_lds16(gSrc + 64 * DIM + k0, bDst + 2048);
        gl_lds16(uSrc + k0, bDst + 4096);
        gl_lds16(uSrc + 64 * DIM + k0, bDst + 6144);
        __syncthreads();
        bf16x8 a[4], bg[2], bu[2];
#pragma unroll
        for (int mg = 0; mg < 4; ++mg)
            a[mg] = *(const bf16x8*)(As + (mg * 16 + m) * 32 + quad * 8);
#pragma unroll
        for (int j = 0; j < 2; ++j) {
            bg[j] = *(const bf16x8*)(Bs + (w * 32 + j * 16 + m) * 32 + quad * 8);
            bu[j] = *(const bf16x8*)(Bs + (128 + w * 32 + j * 16 + m) * 32 + quad * 8);
        }
#pragma unroll
        for (int j = 0; j < 2; ++j)
#pragma unroll
            for (int mg = 0; mg < 4; ++mg) {
                aG[mg][j] = MFMA16(a[mg], bg[j], aG[mg][j]);
                aU[mg][j] = MFMA16(a[mg], bu[j], aU[mg][j]);
            }
        __syncthreads();
    }

#pragma unroll
    for (int mg = 0; mg < 4; ++mg)
#pragma unroll
        for (int j = 0; j < 2; ++j)
#pragma unroll
            for (int r4 = 0; r4 < 4; ++r4) {
                float gv = aG[mg][j][r4], uv = aU[mg][j][r4];
                float h = gv / (1.f + __expf(-gv)) * uv;
                hout[(size_t)(mg * 16 + quad * 4 + r4) * hstride + w * 32 + j * 16 + m] = (bf16)h;
            }
}

// ---------------------------------------------------------------- phase 2 (routed down)
__global__ __launch_bounds__(256, 3)
void phase2(const bf16* __restrict__ Hg, const bf16* __restrict__ wd,
            const int* __restrict__ counts, const float* __restrict__ slist,
            const int* __restrict__ items, const int* __restrict__ nitems,
            bf16* __restrict__ Od) {
    __shared__ __align__(16) bf16 As[64 * 32];
    __shared__ __align__(16) bf16 Bs[256 * 32];
    __shared__ float ssc[64];

    int rbk = blockIdx.x;
    if (rbk >= *nitems) return;
    int it = items[rbk];
    int e = it >> 24, t = (it >> 16) & 0xff, rowbase = it & 0xffff;
    int n0 = blockIdx.y * 256;
    int cnt = counts[e];

    int tid = threadIdx.x;
    if (tid < 64) {
        int li = t * 64 + tid;
        ssc[tid] = (li < cnt) ? slist[(size_t)e * N_TOK + li] : 0.f;
    }

    int r = tid >> 2, chunk = (tid & 3) * 8;
    const bf16* aSrc = Hg + (size_t)(rowbase + r) * H_E + chunk;
    const bf16* bSrc = wd + (size_t)e * DIM * H_E + (size_t)(n0 + r) * H_E + chunk;
    bf16* aDst = As + tid * 8;
    bf16* bDst = Bs + tid * 8;

    int w = tid >> 6, lane = tid & 63, m = lane & 15, quad = lane >> 4;
    floatx4 acc[4][4] = {{{0}}};

    for (int k0 = 0; k0 < H_E; k0 += 32) {
        gl_lds16(aSrc + k0, aDst);
#pragma unroll
        for (int p = 0; p < 4; ++p)
            gl_lds16(bSrc + (size_t)p * 64 * H_E + k0, bDst + p * 2048);
        __syncthreads();
        bf16x8 a[4], bb[4];
#pragma unroll
        for (int mg = 0; mg < 4; ++mg)
            a[mg] = *(const bf16x8*)(As + (mg * 16 + m) * 32 + quad * 8);
#pragma unroll
        for (int ng = 0; ng < 4; ++ng)
            bb[ng] = *(const bf16x8*)(Bs + (w * 64 + ng * 16 + m) * 32 + quad * 8);
#pragma unroll
        for (int ng = 0; ng < 4; ++ng)
#pragma unroll
            for (int mg = 0; mg < 4; ++mg)
                acc[mg][ng] = MFMA16(a[mg], bb[ng], acc[mg][ng]);
        __syncthreads();
    }

#pragma unroll
    for (int mg = 0; mg < 4; ++mg)
#pragma unroll
        for (int r4 = 0; r4 < 4; ++r4) {
            int row = mg * 16 + quad * 4 + r4;
            float sc = ssc[row];
            bf16* op = Od + (size_t)(rowbase + row) * DIM + n0 + w * 64 + m;
#pragma unroll
            for (int ng = 0; ng < 4; ++ng)
                op[ng * 16] = (bf16)(acc[mg][ng][r4] * sc);
        }
}

// ---------------------------------------------------------------- shared down + routed reduce
__global__ __launch_bounds__(256, 3)
void shared_down(const bf16* __restrict__ Hs, const bf16* __restrict__ sd,
                 const bf16* __restrict__ Od, const int* __restrict__ tok2slot,
                 const int* __restrict__ expbase, float* __restrict__ out) {
    __shared__ __align__(16) bf16 As[64 * 32];
    __shared__ __align__(16) bf16 Bs[256 * 32];
    __shared__ int srow[64][4];

    int t0 = blockIdx.x * 64;
    int n0 = blockIdx.y * 256;
    int tid = threadIdx.x;

    if (tid < 64) {
        const int* t2s = tok2slot + (size_t)(t0 + tid) * 4;
#pragma unroll
        for (int k = 0; k < 4; ++k) {
            int v = t2s[k];
            srow[tid][k] = expbase[v >> 16] + (v & 0xffff);
        }
    }

    int r = tid >> 2, chunk = (tid & 3) * 8;
    const bf16* aSrc = Hs + (size_t)(t0 + r) * HS + chunk;
    const bf16* bSrc = sd + (size_t)(n0 + r) * HS + chunk;
    bf16* aDst = As + tid * 8;
    bf16* bDst = Bs + tid * 8;

    int w = tid >> 6, lane = tid & 63, m = lane & 15, quad = lane >> 4;
    floatx4 acc[4][4] = {{{0}}};

    for (int k0 = 0; k0 < HS; k0 += 32) {
        gl_lds16(aSrc + k0, aDst);
#pragma unroll
        for (int p = 0; p < 4; ++p)
            gl_lds16(bSrc + (size_t)p * 64 * HS + k0, bDst + p * 2048);
        __syncthreads();
        bf16x8 a[4], bb[4];
#pragma unroll
        for (int mg = 0; mg < 4; ++mg)
            a[mg] = *(const bf16x8*)(As + (mg * 16 + m) * 32 + quad * 8);
#pragma unroll
        for (int ng = 0; ng < 4; ++ng)
            bb[ng] = *(const bf16x8*)(Bs + (w * 64 + ng * 16 + m) * 32 + quad * 8);
#pragma unroll
        for (int ng = 0; ng < 4; ++ng)
#pragma unroll
            for (int mg = 0; mg < 4; ++mg)
                acc[mg][ng] = MFMA16(a[mg], bb[ng], acc[mg][ng]);
        __syncthreads();
    }

#pragma unroll
    for (int mg = 0; mg < 4; ++mg)
#pragma unroll
        for (int r4 = 0; r4 < 4; ++r4) {
            int rl = mg * 16 + quad * 4 + r4;
            size_t r0 = (size_t)srow[rl][0] * DIM;
            size_t r1 = (size_t)srow[rl][1] * DIM;
            size_t r2 = (size_t)srow[rl][2] * DIM;
            size_t r3 = (size_t)srow[rl][3] * DIM;
            float* op = out + (size_t)(t0 + rl) * DIM + n0 + w * 64 + m;
#pragma unroll
            for (int ng = 0; ng < 4; ++ng) {
                int col = n0 + w * 64 + ng * 16 + m;
                float v = acc[mg][ng][r4]
                        + (float)Od[r0 + col] + (float)Od[r1 + col]
                        + (float)Od[r2 + col] + (float)Od[r3 + col];
                op[ng * 16] = v;
            }
        }
}

// ---------------------------------------------------------------- launch
extern "C" void kernel_launch(void* const* d_in, const int* in_sizes, int n_in,
                              void* d_out, int out_size, void* d_ws, size_t ws_size,
                              hipStream_t stream) {
    (void)in_sizes; (void)n_in; (void)out_size; (void)ws_size;
    const float* x   = (const float*)d_in[0];
    const float* rw  = (const float*)d_in[1];
    const float* rb  = (const float*)d_in[2];
    const float* gw  = (const float*)d_in[3];
    const float* uw  = (const float*)d_in[4];
    const float* dw  = (const float*)d_in[5];
    const float* sgw = (const float*)d_in[6];
    const float* suw = (const float*)d_in[7];
    const float* sdw = (const float*)d_in[8];
    float* out = (float*)d_out;

    char* ws = (char*)d_ws;
    size_t o = 0;
    bf16* xb  = (bf16*)(ws + o); o += (size_t)N_TOK * DIM * 2;
    bf16* wgb = (bf16*)(ws + o); o += (size_t)E_R * H_E * DIM * 2;
    bf16* wub = (bf16*)(ws + o); o += (size_t)E_R * H_E * DIM * 2;
    bf16* wdb = (bf16*)(ws + o); o += (size_t)E_R * DIM * H_E * 2;
    bf16* sgb = (bf16*)(ws + o); o += (size_t)HS * DIM * 2;
    bf16* sub = (bf16*)(ws + o); o += (size_t)HS * DIM * 2;
    bf16* sdb = (bf16*)(ws + o); o += (size_t)DIM * HS * 2;
    bf16* Hg  = (bf16*)(ws + o); o += (size_t)MAXSLOT * H_E * 2;
    bf16* Hs  = (bf16*)(ws + o); o += (size_t)N_TOK * HS * 2;
    bf16* Od  = (bf16*)(ws + o); o += (size_t)MAXSLOT * DIM * 2;
    float* partial = (float*)(ws + o); o += (size_t)RKS * N_TOK * 32 * 4;
    int*   counts = (int*)(ws + o);   o += 256;
    int*   tlist  = (int*)(ws + o);   o += (size_t)E_R * N_TOK * 4;
    float* slist  = (float*)(ws + o); o += (size_t)E_R * N_TOK * 4;
    int*   tok2slot = (int*)(ws + o); o += (size_t)N_TOK * 4 * 4;
    int*   items  = (int*)(ws + o);   o += 4096;
    int*   nitems = (int*)(ws + o);   o += 64;
    int*   expbase = (int*)(ws + o);  o += 256;

    hipMemsetAsync(counts, 0, E_R * sizeof(int), stream);

    router_gemm<<<dim3(N_TOK / 64, RKS), 256, 0, stream>>>(x, rw, partial);
    router_fin<<<N_TOK / 256, 256, 0, stream>>>(partial, rb, counts, tlist, slist,
                                                tok2slot);
    cvt_all<<<11008, 256, 0, stream>>>(x, gw, uw, dw, sgw, suw, sdw,
                                       xb, wgb, wub, wdb, sgb, sub, sdb);
    wq_build<<<1, 64, 0, stream>>>(counts, items, nitems, expbase);
    phase1<<<1056, 256, 0, stream>>>(xb, wgb, wub, sgb, sub, counts, tlist,
                                     items, nitems, Hg, Hs);
    phase2<<<dim3(544, 4), 256, 0, stream>>>(Hg, wdb, counts, slist,
                                             items, nitems, Od);
    shared_down<<<dim3(N_TOK / 64, 4), 256, 0, stream>>>(Hs, sdb, Od, tok2slot,
                                                         expbase, out);
}